// Round 2
// baseline (2204.582 us; speedup 1.0000x reference)
//
#include <hip/hip_runtime.h>

typedef unsigned short u16;
typedef __bf16 bf16x8 __attribute__((ext_vector_type(8)));
typedef float f32x4 __attribute__((ext_vector_type(4)));

__device__ __forceinline__ float b2f(u16 u) { return __uint_as_float(((unsigned)u) << 16); }
__device__ __forceinline__ u16 f2b(float f) {
  unsigned i = __float_as_uint(f);
  return (u16)((i + 0x7FFFu + ((i >> 16) & 1u)) >> 16);
}
__device__ __forceinline__ float sane(float x, float lim) {
  float y = fminf(fmaxf(x, -lim), lim);
  return (y != y) ? 0.0f : y;
}
__device__ __forceinline__ float wred(float x) {
#pragma unroll
  for (int m = 1; m < 64; m <<= 1) x += __shfl_xor(x, m, 64);
  return x;
}

// raw barrier that waits LDS ops only (keeps global-load prefetch in flight,
// unlike __syncthreads which drains vmcnt(0))
__device__ __forceinline__ void bar_lgkm() {
  asm volatile("s_waitcnt lgkmcnt(0)" ::: "memory");
  __builtin_amdgcn_s_barrier();
  asm volatile("" ::: "memory");
}

// ---------------- dtype detect ----------------
__global__ void detect_dtype(const unsigned* __restrict__ g_ones, int* __restrict__ flag) {
  *flag = (g_ones[0] == 0x3F800000u) ? 1 : 0;
}

// ---------------- batched convert: all float inputs -> canonical bf16 ----------------
#define NSEG 23
struct CvtArgs {
  const void* src[NSEG];
  int start[NSEG + 1];
};
__global__ __launch_bounds__(256) void cvt_all(CvtArgs a, u16* __restrict__ dst,
                                               const int* __restrict__ flag) {
  const int i = blockIdx.x * 256 + threadIdx.x;
  if (i >= a.start[NSEG]) return;
  int k = 0;
#pragma unroll
  for (int s = 1; s < NSEG; ++s) k += (i >= a.start[s]) ? 1 : 0;
  const int j = i - a.start[k];
  u16 v;
  if (*flag) v = f2b(((const float*)a.src[k])[j]);
  else       v = ((const u16*)a.src[k])[j];
  dst[i] = v;
}

// ---------------- weight transpose ----------------
__global__ __launch_bounds__(256) void transpose_bf16(const u16* __restrict__ src,
                                                      u16* __restrict__ dst, int R, int C) {
  __shared__ u16 tile[32][33];
  const long zo = (long)blockIdx.z * R * C;
  src += zo; dst += zo;
  const int tx = threadIdx.x & 31, ty = threadIdx.x >> 5;
  const int c0 = blockIdx.x * 32, r0 = blockIdx.y * 32;
#pragma unroll
  for (int i = 0; i < 32; i += 8) tile[ty + i][tx] = src[(r0 + ty + i) * C + c0 + tx];
  __syncthreads();
#pragma unroll
  for (int i = 0; i < 32; i += 8) dst[(c0 + ty + i) * R + r0 + tx] = tile[tx][ty + i];
}

// ---------------- embedding + layernorm ----------------
__global__ __launch_bounds__(256) void embed_ln(const int* __restrict__ ids,
    const u16* __restrict__ inW, const u16* __restrict__ inB, const u16* __restrict__ tokE,
    const u16* __restrict__ g, const u16* __restrict__ bb, u16* __restrict__ xb) {
  const int wave = threadIdx.x >> 6, lane = threadIdx.x & 63;
  const int n = blockIdx.x * 4 + wave;
  float idv[6];
#pragma unroll
  for (int f = 0; f < 6; ++f) idv[f] = (float)ids[n * 6 + f];
  float v[8]; float s = 0.f;
#pragma unroll
  for (int j = 0; j < 8; ++j) {
    const int d = j * 64 + lane;
    float a = b2f(inB[d]) + b2f(tokE[d]);
#pragma unroll
    for (int f = 0; f < 6; ++f) a += idv[f] * b2f(inW[f * 512 + d]);
    v[j] = a; s += a;
  }
  s = wred(s);
  const float mu = s * (1.f / 512.f);
  float q = 0.f;
#pragma unroll
  for (int j = 0; j < 8; ++j) { float t = v[j] - mu; q += t * t; }
  q = wred(q);
  const float rstd = rsqrtf(q * (1.f / 512.f) + 1e-12f);
#pragma unroll
  for (int j = 0; j < 8; ++j) {
    const int d = j * 64 + lane;
    xb[n * 512 + d] = f2b(sane((v[j] - mu) * rstd * b2f(g[d]) + b2f(bb[d]), 6e4f));
  }
}

// ---------------- residual add + layernorm ----------------
__global__ __launch_bounds__(256) void add_ln(const u16* __restrict__ xin,
    const u16* __restrict__ add, const u16* __restrict__ g, const u16* __restrict__ bb,
    void* __restrict__ outp, const int* __restrict__ flag, int isfinal) {
  const int wave = threadIdx.x >> 6, lane = threadIdx.x & 63;
  const int n = blockIdx.x * 4 + wave;
  const int base = n * 512 + lane * 8;
  uint4 xa = *(const uint4*)&xin[base];
  uint4 aa = *(const uint4*)&add[base];
  const unsigned* xw = (const unsigned*)&xa;
  const unsigned* aw = (const unsigned*)&aa;
  float v[8]; float s = 0.f;
#pragma unroll
  for (int w = 0; w < 4; ++w) {
    float x0 = b2f((u16)(xw[w] & 0xffff)) + b2f((u16)(aw[w] & 0xffff));
    float x1 = b2f((u16)(xw[w] >> 16)) + b2f((u16)(aw[w] >> 16));
    v[w * 2] = x0; v[w * 2 + 1] = x1; s += x0 + x1;
  }
  s = wred(s);
  const float mu = s * (1.f / 512.f);
  float qs = 0.f;
#pragma unroll
  for (int j = 0; j < 8; ++j) { float t = v[j] - mu; qs += t * t; }
  qs = wred(qs);
  const float rstd = rsqrtf(qs * (1.f / 512.f) + 1e-12f);
  uint4 ga = *(const uint4*)&g[lane * 8];
  uint4 ba = *(const uint4*)&bb[lane * 8];
  const unsigned* gw = (const unsigned*)&ga;
  const unsigned* bw = (const unsigned*)&ba;
  float y[8];
#pragma unroll
  for (int w = 0; w < 4; ++w) {
    y[w * 2]     = sane((v[w * 2] - mu) * rstd * b2f((u16)(gw[w] & 0xffff)) + b2f((u16)(bw[w] & 0xffff)), 6e4f);
    y[w * 2 + 1] = sane((v[w * 2 + 1] - mu) * rstd * b2f((u16)(gw[w] >> 16)) + b2f((u16)(bw[w] >> 16)), 6e4f);
  }
  if (isfinal && *flag) {
    float* of = (float*)outp;
    float4 o0, o1;
    o0.x = y[0]; o0.y = y[1]; o0.z = y[2]; o0.w = y[3];
    o1.x = y[4]; o1.y = y[5]; o1.z = y[6]; o1.w = y[7];
    *(float4*)&of[base] = o0;
    *(float4*)&of[base + 4] = o1;
  } else {
    uint4 o;
    unsigned* ow = (unsigned*)&o;
#pragma unroll
    for (int w = 0; w < 4; ++w)
      ow[w] = (unsigned)f2b(y[w * 2]) | ((unsigned)f2b(y[w * 2 + 1]) << 16);
    *(uint4*)&((u16*)outp)[base] = o;
  }
}

// ---------------- MFMA GEMM: C = A @ BT^T + bias; padded LDS (stride 40) ----------------
enum { EPI_ROW, EPI_GELU, EPI_QKH, EPI_VT };

template <int EPI>
__global__ __launch_bounds__(256)
void gemm_bt(const u16* __restrict__ A, const u16* __restrict__ BT,
             const u16* __restrict__ bias, u16* __restrict__ out, int K, int ldo) {
  __shared__ alignas(16) u16 sA[128 * 40];
  __shared__ alignas(16) u16 sB[128 * 40];
  const int tid = threadIdx.x;
  const int wave = tid >> 6, lane = tid & 63;
  const int quad = lane >> 4, li = lane & 15;
  const int m0 = blockIdx.x * 128, n0 = blockIdx.y * 128;
  const u16* Ab = A + m0 * K;
  const u16* Bb = BT + n0 * K;
  const int wm = wave >> 1, wn = wave & 1;
  const int r0 = tid >> 2, kc0 = tid & 3;
  f32x4 acc[4][4] = {};
  for (int kt = 0; kt < K; kt += 32) {
    __syncthreads();
    uint4 a0 = *(const uint4*)(Ab + r0 * K + kt + kc0 * 8);
    uint4 a1 = *(const uint4*)(Ab + (r0 + 64) * K + kt + kc0 * 8);
    uint4 b0 = *(const uint4*)(Bb + r0 * K + kt + kc0 * 8);
    uint4 b1 = *(const uint4*)(Bb + (r0 + 64) * K + kt + kc0 * 8);
    *(uint4*)&sA[r0 * 40 + kc0 * 8] = a0;
    *(uint4*)&sA[(r0 + 64) * 40 + kc0 * 8] = a1;
    *(uint4*)&sB[r0 * 40 + kc0 * 8] = b0;
    *(uint4*)&sB[(r0 + 64) * 40 + kc0 * 8] = b1;
    __syncthreads();
    bf16x8 aF[4], bF[4];
#pragma unroll
    for (int mt = 0; mt < 4; ++mt)
      aF[mt] = *(const bf16x8*)&sA[(wm * 64 + mt * 16 + li) * 40 + quad * 8];
#pragma unroll
    for (int nt = 0; nt < 4; ++nt)
      bF[nt] = *(const bf16x8*)&sB[(wn * 64 + nt * 16 + li) * 40 + quad * 8];
#pragma unroll
    for (int mt = 0; mt < 4; ++mt)
#pragma unroll
      for (int nt = 0; nt < 4; ++nt)
        acc[mt][nt] = __builtin_amdgcn_mfma_f32_16x16x32_bf16(aF[mt], bF[nt], acc[mt][nt], 0, 0, 0);
  }
  if constexpr (EPI == EPI_VT) {
    // transpose through LDS for coalesced [bh][dh][s] stores
    __shared__ alignas(16) u16 sE[128 * 136];
#pragma unroll
    for (int mt = 0; mt < 4; ++mt)
#pragma unroll
      for (int nt = 0; nt < 4; ++nt)
#pragma unroll
        for (int r = 0; r < 4; ++r) {
          const int ml = wm * 64 + mt * 16 + quad * 4 + r;
          const int nl = wn * 64 + nt * 16 + li;
          float v = sane(acc[mt][nt][r] + b2f(bias[n0 + nl]), 6e4f);
          sE[nl * 136 + ml] = f2b(v);
        }
    __syncthreads();
    const int bht = (m0 >> 8) * 4 + (n0 >> 7);
    const int s0 = m0 & 255;
    const int dh = tid >> 1, half = tid & 1;
    u16* orow = out + ((size_t)bht * 128 + dh) * 256 + s0 + half * 64;
    const u16* srow = &sE[dh * 136 + half * 64];
#pragma unroll
    for (int i = 0; i < 8; ++i)
      *(uint4*)&orow[i * 8] = *(const uint4*)&srow[i * 8];
  } else {
#pragma unroll
    for (int mt = 0; mt < 4; ++mt) {
#pragma unroll
      for (int nt = 0; nt < 4; ++nt) {
#pragma unroll
        for (int r = 0; r < 4; ++r) {
          const int m = m0 + wm * 64 + mt * 16 + quad * 4 + r;
          const int n = n0 + wn * 64 + nt * 16 + li;
          float v = sane(acc[mt][nt][r] + b2f(bias[n]), 6e4f);
          if constexpr (EPI == EPI_GELU) v = 0.5f * v * (1.0f + erff(v * 0.70710678118654752f));
          if constexpr (EPI == EPI_ROW || EPI == EPI_GELU) {
            out[m * ldo + n] = f2b(v);
          } else { // EPI_QKH -> [bh][s][dh]
            out[(((m >> 8) * 4 + (n >> 7)) * 256 + (m & 255)) * 128 + (n & 127)] = f2b(v);
          }
        }
      }
    }
  }
}

// ---------------- fused attention ----------------
// grid = dim3(4, 512): blockIdx.x = lt (fast -> same-bh blocks adjacent for K/V L2 reuse).
// LDS layout (81920 B total = exactly 2 blocks/CU):
//   sKV 16384 B : K chunk [64 rows][256 B] XOR-swz   |  V chunk [128 rows][128 B] XOR-swz
//   sPB 32768 B : bands sT3 [64][128B]swz @0, sT2 @8192  |  later P [64][512B]swz
//   sDE 32768 B : de tile rows [rb, rb+128) [128 rows][256 B] XOR-swz | later ctx-out tile
// XOR swizzle: byte ^= (row&7)<<4  (write and read sides identical).
__global__ __launch_bounds__(256, 2)
void attn_kernel(const u16* __restrict__ qb, const u16* __restrict__ kb,
                 const u16* __restrict__ vtb, const u16* __restrict__ de,
                 const u16* __restrict__ mask, u16* __restrict__ ctx) {
  __shared__ alignas(16) char sKV[16384];
  __shared__ alignas(16) char sPB[32768];
  __shared__ alignas(16) char sDE[32768];
  const int tid = threadIdx.x;
  const int wave = tid >> 6, lane = tid & 63, quad = lane >> 4, li = lane & 15;
  const int lt = blockIdx.x;
  const int bh = blockIdx.y;
  const int b = bh >> 2, h = bh & 3;
  const int l0 = lt * 64;
  const u16* Qg = qb + (size_t)bh * 256 * 128;
  const u16* Kg = kb + (size_t)bh * 256 * 128;
  const u16* Vg = vtb + (size_t)bh * 128 * 256;
  const float scale = 0.08838834764831845f;

  // ---- prefetch K chunk 0 + de tile 0 into regs ----
  const int krow = tid >> 2, kq4 = tid & 3;
  const int drw = tid >> 4, dcl = tid & 15;  // de staging: 16 threads/row
  uint4 kreg[2][4];
  uint4 dreg[2][8];
#pragma unroll
  for (int i = 0; i < 4; ++i)
    kreg[0][i] = *(const uint4*)&Kg[krow * 128 + kq4 * 8 + i * 32];
  {
    const int rb0 = l0 + 192;  // c = 0
#pragma unroll
    for (int i = 0; i < 8; ++i) {
      const int rr = i * 16 + drw;
      const int g = min(rb0 + rr, 510);
      dreg[0][i] = *(const uint4*)&de[g * 128 + dcl * 8];
    }
  }

  bf16x8 aQ[4];
#pragma unroll
  for (int kt = 0; kt < 4; ++kt)
    aQ[kt] = *(const bf16x8*)&Qg[(l0 + wave * 16 + li) * 128 + kt * 32 + quad * 8];

  f32x4 sc[16] = {};
#pragma unroll
  for (int c = 0; c < 4; ++c) {
    const int rb = l0 - c * 64 + 192;  // de tile base row for this chunk
    if (c > 0) bar_lgkm();  // prev chunk's LDS readers fully drained
    // write staged K chunk [64][256B] swz
#pragma unroll
    for (int i = 0; i < 4; ++i)
      *(uint4*)&sKV[(krow * 256 + kq4 * 16 + i * 64) ^ ((krow & 7) << 4)] = kreg[c & 1][i];
    // write staged de tile [128][256B] swz
#pragma unroll
    for (int i = 0; i < 8; ++i) {
      const int rr = i * 16 + drw;
      *(uint4*)&sDE[(rr * 256 + dcl * 16) ^ ((rr & 7) << 4)] = dreg[c & 1][i];
    }
    // issue next chunk's global loads BEFORE compute (stay in flight across raw barriers)
    if (c < 3) {
#pragma unroll
      for (int i = 0; i < 4; ++i)
        kreg[(c + 1) & 1][i] =
            *(const uint4*)&Kg[((c + 1) * 64 + krow) * 128 + kq4 * 8 + i * 32];
      const int rbn = rb - 64;
#pragma unroll
      for (int i = 0; i < 8; ++i) {
        const int rr = i * 16 + drw;
        const int g = min(rbn + rr, 510);
        dreg[(c + 1) & 1][i] = *(const uint4*)&de[g * 128 + dcl * 8];
      }
    }
    bar_lgkm();
    __builtin_amdgcn_s_setprio(1);
    // QK^T
#pragma unroll
    for (int kt = 0; kt < 4; ++kt) {
#pragma unroll
      for (int nt = 0; nt < 4; ++nt) {
        const int row = nt * 16 + li;
        bf16x8 bK = *(const bf16x8*)&sKV[(row * 256 + kt * 64 + quad * 16) ^ ((row & 7) << 4)];
        sc[c * 4 + nt] = __builtin_amdgcn_mfma_f32_16x16x32_bf16(aQ[kt], bK, sc[c * 4 + nt], 0, 0, 0);
      }
    }
    // term3: G3[r][p] = k[r]·de[p]; banded to sT3[rL][j]
    {
      f32x4 g3[5] = {};
      const int Ab = l0 - (c * 64 + wave * 16) + 240;
#pragma unroll
      for (int kt = 0; kt < 4; ++kt) {
        const int arow = wave * 16 + li;
        bf16x8 aK = *(const bf16x8*)&sKV[(arow * 256 + kt * 64 + quad * 16) ^ ((arow & 7) << 4)];
#pragma unroll
        for (int pt = 0; pt < 5; ++pt) {
          const int prow = min(Ab + pt * 16 + li, 510);
          const int rr = prow - rb;
          bf16x8 bD = *(const bf16x8*)&sDE[(rr * 256 + kt * 64 + quad * 16) ^ ((rr & 7) << 4)];
          g3[pt] = __builtin_amdgcn_mfma_f32_16x16x32_bf16(aK, bD, g3[pt], 0, 0, 0);
        }
      }
#pragma unroll
      for (int pt = 0; pt < 5; ++pt)
#pragma unroll
        for (int r = 0; r < 4; ++r) {
          const int rL = wave * 16 + quad * 4 + r;
          const int j = pt * 16 + li + quad * 4 + r - 15;
          if ((unsigned)j < 64u)
            *(u16*)&sPB[(rL * 128 + j * 2) ^ ((rL & 7) << 4)] = f2b(g3[pt][r]);
        }
    }
    // term2: G2[l][p] = q[l]·de[p]; banded to sT2[lL][rcol]
    {
      f32x4 g2[5] = {};
      const int A2 = rb + wave * 16;
#pragma unroll
      for (int kt = 0; kt < 4; ++kt) {
#pragma unroll
        for (int pt = 0; pt < 5; ++pt) {
          const int prow = min(A2 + pt * 16 + li, 510);
          const int rr = prow - rb;
          bf16x8 bD = *(const bf16x8*)&sDE[(rr * 256 + kt * 64 + quad * 16) ^ ((rr & 7) << 4)];
          g2[pt] = __builtin_amdgcn_mfma_f32_16x16x32_bf16(aQ[kt], bD, g2[pt], 0, 0, 0);
        }
      }
      __builtin_amdgcn_s_setprio(0);
#pragma unroll
      for (int pt = 0; pt < 5; ++pt)
#pragma unroll
        for (int r = 0; r < 4; ++r) {
          const int lL = wave * 16 + quad * 4 + r;
          const int rcol = quad * 4 + r + 63 - pt * 16 - li;
          if ((unsigned)rcol < 64u)
            *(u16*)&sPB[8192 + ((lL * 128 + rcol * 2) ^ ((lL & 7) << 4))] = f2b(g2[pt][r]);
        }
    }
    bar_lgkm();  // band writes visible
#pragma unroll
    for (int t2 = 0; t2 < 4; ++t2)
#pragma unroll
      for (int r = 0; r < 4; ++r) {
        const int myl = wave * 16 + quad * 4 + r;
        const int r3 = t2 * 16 + li;
        float v3 = sane(b2f(*(const u16*)&sPB[(r3 * 128 + myl * 2) ^ ((r3 & 7) << 4)]), 1e4f);
        float v2 = sane(b2f(*(const u16*)&sPB[8192 + ((myl * 128 + r3 * 2) ^ ((myl & 7) << 4))]), 1e4f);
        sc[c * 4 + t2][r] += v3 + v2;
      }
  }

  // ---- issue V chunk 0 prefetch; overlaps mask load + softmax VALU ----
  const int vrow = tid >> 1, vhalf = tid & 1;
  uint4 vreg[2][4];
#pragma unroll
  for (int i = 0; i < 4; ++i)
    vreg[0][i] = *(const uint4*)&Vg[vrow * 256 + vhalf * 32 + i * 8];

  float mbv[16];
#pragma unroll
  for (int t = 0; t < 16; ++t)
    mbv[t] = (1.0f - b2f(mask[b * 256 + t * 16 + li])) * -1e9f;

  // logits + softmax
#pragma unroll
  for (int t = 0; t < 16; ++t)
#pragma unroll
    for (int r = 0; r < 4; ++r) sc[t][r] = sane(sc[t][r] * scale + mbv[t], 2e9f);
#pragma unroll
  for (int r = 0; r < 4; ++r) {
    float mx = -3.0e38f;
#pragma unroll
    for (int t = 0; t < 16; ++t) mx = fmaxf(mx, sc[t][r]);
#pragma unroll
    for (int m = 1; m < 16; m <<= 1) mx = fmaxf(mx, __shfl_xor(mx, m, 64));
    float s = 0.f;
#pragma unroll
    for (int t = 0; t < 16; ++t) { float e = __expf(sc[t][r] - mx); sc[t][r] = e; s += e; }
#pragma unroll
    for (int m = 1; m < 16; m <<= 1) s += __shfl_xor(s, m, 64);
    const float inv = 1.f / s;
#pragma unroll
    for (int t = 0; t < 16; ++t) sc[t][r] *= inv;
  }

  bar_lgkm();  // band readers done; reuse sPB as P [64][512B] swz
#pragma unroll
  for (int t = 0; t < 16; ++t)
#pragma unroll
    for (int r = 0; r < 4; ++r) {
      const int row = wave * 16 + quad * 4 + r;
      *(u16*)&sPB[(row * 512 + (t * 16 + li) * 2) ^ ((row & 7) << 4)] = f2b(sc[t][r]);
    }

  // PV: V chunks [128 rows][128 B] swz
  f32x4 ct[8] = {};
#pragma unroll
  for (int c = 0; c < 4; ++c) {
    if (c > 0) bar_lgkm();  // prev chunk's PV reads drained
#pragma unroll
    for (int i = 0; i < 4; ++i)
      *(uint4*)&sKV[(vrow * 128 + vhalf * 64 + i * 16) ^ ((vrow & 7) << 4)] = vreg[c & 1][i];
    if (c < 3) {
#pragma unroll
      for (int i = 0; i < 4; ++i)
        vreg[(c + 1) & 1][i] =
            *(const uint4*)&Vg[vrow * 256 + (c + 1) * 64 + vhalf * 32 + i * 8];
    }
    bar_lgkm();  // covers P writes (c==0) + V chunk writes
    __builtin_amdgcn_s_setprio(1);
#pragma unroll
    for (int ks = 0; ks < 2; ++ks) {
      const int prow = wave * 16 + li;
      bf16x8 aF = *(const bf16x8*)&sPB[(prow * 512 + c * 128 + ks * 64 + quad * 16) ^ ((prow & 7) << 4)];
#pragma unroll
      for (int nt = 0; nt < 8; ++nt) {
        const int row = nt * 16 + li;
        bf16x8 bV = *(const bf16x8*)&sKV[(row * 128 + ks * 64 + quad * 16) ^ ((row & 7) << 4)];
        ct[nt] = __builtin_amdgcn_mfma_f32_16x16x32_bf16(aF, bV, ct[nt], 0, 0, 0);
      }
    }
    __builtin_amdgcn_s_setprio(0);
  }

  // ctx epilogue: write [64 rows][256B] swz tile into sDE (free since QK phase).
  // Writer wave == reader wave for each row => no barrier needed, lgkmcnt only.
#pragma unroll
  for (int nt = 0; nt < 8; ++nt)
#pragma unroll
    for (int r = 0; r < 4; ++r) {
      const int row = wave * 16 + quad * 4 + r;
      *(u16*)&sDE[(row * 256 + (nt * 16 + li) * 2) ^ ((row & 7) << 4)] = f2b(sane(ct[nt][r], 1e4f));
    }
  asm volatile("s_waitcnt lgkmcnt(0)" ::: "memory");
  __builtin_amdgcn_sched_barrier(0);
  {  // coalesced ctx store: 4 uint4 = 32 elems/thread (reads own wave's rows)
    const int row = tid >> 2, seg = tid & 3;
    u16* orow = ctx + ((size_t)(b * 256 + l0 + row)) * 512 + h * 128 + seg * 32;
#pragma unroll
    for (int i = 0; i < 4; ++i) {
      uint4 v = *(const uint4*)&sDE[(row * 256 + seg * 64 + i * 16) ^ ((row & 7) << 4)];
      *(uint4*)&orow[i * 8] = v;
    }
  }
}

// ---------------- orchestration ----------------
extern "C" void kernel_launch(void* const* d_in, const int* in_sizes, int n_in,
                              void* d_out, int out_size, void* d_ws, size_t ws_size,
                              hipStream_t stream) {
  (void)in_sizes; (void)n_in; (void)out_size; (void)ws_size;
  const int* ids = (const int*)d_in[0];

  static const int ns[NSEG] = {
      32768, 3072, 512, 512, 512, 512, 65408,
      1048576, 2048, 1048576, 2048, 1048576, 2048, 1048576, 2048,
      2048, 2048, 262144, 512, 262144, 2048, 2048, 2048
  };
  CvtArgs ca;
  int st[NSEG + 1];
  st[0] = 0;
  for (int k = 0; k < NSEG; ++k) { ca.src[k] = d_in[k + 1]; st[k + 1] = st[k] + ns[k]; }
  for (int k = 0; k <= NSEG; ++k) ca.start[k] = st[k];
  const int total = st[NSEG];

  char* W = (char*)d_ws;
  size_t off = 0;
  auto alloc = [&](size_t bytes) { void* p = W + off; off += (bytes + 255) & ~(size_t)255; return p; };
  u16* canon = (u16*)alloc((size_t)total * 2);
  int* flag  = (int*)alloc(256);
  const size_t ND = (size_t)32768 * 512;
  u16* xb   = (u16*)alloc(ND * 2);
  u16* qbf  = (u16*)alloc(ND * 2);
  u16* kbf  = (u16*)alloc(ND * 2);
  u16* vtb  = (u16*)alloc(ND * 2);
  u16* wqT  = (u16*)alloc((size_t)4 * 512 * 512 * 2);
  u16* wkT  = (u16*)alloc((size_t)4 * 512 * 512 * 2);
  u16* wvT  = (u16*)alloc((size_t)4 * 512 * 512 * 2);
  u16* woT  = (u16*)alloc((size_t)4 * 512 * 512 * 2);
  u16* wiT  = (u16*)alloc((size_t)4 * 512 * 128 * 2);
  u16* wo2T = (u16*)alloc((size_t)4 * 128 * 512 * 2);
  u16* ctxb = (u16*)d_out;

  const u16* mask = canon + st[0];
  const u16* inW  = canon + st[1];
  const u16* inB  = canon + st[2];
  const u16* tokE = canon + st[3];
  const u16* eg   = canon + st[4];
  const u16* ebb  = canon + st[5];
  const u16* de   = canon + st[6];
  const u16* Wq   = canon + st[7];
  const u16* bq   = canon + st[8];
  const u16* Wk   = canon + st[9];
  const u16* bk   = canon + st[10];
  const u16* Wv   = canon + st[11];
  const u16* bv   = canon + st[12];
  const u16* Wo   = canon + st[13];
  const u16* bo   = canon + st[14];
  const u16* l1g  = canon + st[15];
  const u16* l1b  = canon + st[16];
  const u16* Wi   = canon + st[17];
  const u16* bi   = canon + st[18];
  const u16* Wo2  = canon + st[19];
  const u16* bo2  = canon + st[20];
  const u16* l2g  = canon + st[21];
  const u16* l2b  = canon + st[22];

  dim3 B256(256);
  detect_dtype<<<1, 1, 0, stream>>>((const unsigned*)d_in[5], flag);
  cvt_all<<<(total + 255) / 256, B256, 0, stream>>>(ca, canon, flag);
  transpose_bf16<<<dim3(16, 16, 4), B256, 0, stream>>>(Wq, wqT, 512, 512);
  transpose_bf16<<<dim3(16, 16, 4), B256, 0, stream>>>(Wk, wkT, 512, 512);
  transpose_bf16<<<dim3(16, 16, 4), B256, 0, stream>>>(Wv, wvT, 512, 512);
  transpose_bf16<<<dim3(16, 16, 4), B256, 0, stream>>>(Wo, woT, 512, 512);
  transpose_bf16<<<dim3(4, 16, 4), B256, 0, stream>>>(Wi, wiT, 512, 128);
  transpose_bf16<<<dim3(16, 4, 4), B256, 0, stream>>>(Wo2, wo2T, 128, 512);
  embed_ln<<<8192, B256, 0, stream>>>(ids, inW, inB, tokE, eg, ebb, xb);

  for (int l = 0; l < 4; ++l) {
    gemm_bt<EPI_QKH><<<dim3(256, 4), B256, 0, stream>>>(xb, wqT + l * 512 * 512, bq + l * 512, qbf, 512, 0);
    gemm_bt<EPI_QKH><<<dim3(256, 4), B256, 0, stream>>>(xb, wkT + l * 512 * 512, bk + l * 512, kbf, 512, 0);
    gemm_bt<EPI_VT><<<dim3(256, 4), B256, 0, stream>>>(xb, wvT + l * 512 * 512, bv + l * 512, vtb, 512, 0);
    attn_kernel<<<dim3(4, 512), B256, 0, stream>>>(qbf, kbf, vtb, de, mask, ctxb);
    gemm_bt<EPI_ROW><<<dim3(256, 4), B256, 0, stream>>>(ctxb, woT + l * 512 * 512, bo + l * 512, qbf, 512, 512);
    add_ln<<<8192, B256, 0, stream>>>(xb, qbf, l1g + l * 512, l1b + l * 512, xb, flag, 0);
    gemm_bt<EPI_GELU><<<dim3(256, 1), B256, 0, stream>>>(xb, wiT + l * 512 * 128, bi + l * 128, kbf, 512, 128);
    gemm_bt<EPI_ROW><<<dim3(256, 4), B256, 0, stream>>>(kbf, wo2T + l * 128 * 512, bo2 + l * 512, vtb, 128, 512);
    add_ln<<<8192, B256, 0, stream>>>(xb, vtb, l2g + l * 512, l2b + l * 512,
                                      (l == 3) ? d_out : (void*)xb, flag, (l == 3) ? 1 : 0);
  }
}

// Round 3
// 2070.416 us; speedup vs baseline: 1.0648x; 1.0648x over previous
//
#include <hip/hip_runtime.h>

typedef unsigned short u16;
typedef __bf16 bf16x8 __attribute__((ext_vector_type(8)));
typedef float f32x4 __attribute__((ext_vector_type(4)));

__device__ __forceinline__ float b2f(u16 u) { return __uint_as_float(((unsigned)u) << 16); }
__device__ __forceinline__ u16 f2b(float f) {
  unsigned i = __float_as_uint(f);
  return (u16)((i + 0x7FFFu + ((i >> 16) & 1u)) >> 16);
}
__device__ __forceinline__ float sane(float x, float lim) {
  float y = fminf(fmaxf(x, -lim), lim);
  return (y != y) ? 0.0f : y;
}
__device__ __forceinline__ float wred(float x) {
#pragma unroll
  for (int m = 1; m < 64; m <<= 1) x += __shfl_xor(x, m, 64);
  return x;
}

// raw barrier that waits LDS ops only (keeps global-load prefetch in flight,
// unlike __syncthreads which drains vmcnt(0))
__device__ __forceinline__ void bar_lgkm() {
  asm volatile("s_waitcnt lgkmcnt(0)" ::: "memory");
  __builtin_amdgcn_s_barrier();
  asm volatile("" ::: "memory");
}

// ---------------- dtype detect ----------------
__global__ void detect_dtype(const unsigned* __restrict__ g_ones, int* __restrict__ flag) {
  *flag = (g_ones[0] == 0x3F800000u) ? 1 : 0;
}

// ---------------- batched convert: all float inputs -> canonical bf16 ----------------
#define NSEG 23
struct CvtArgs {
  const void* src[NSEG];
  int start[NSEG + 1];
};
__global__ __launch_bounds__(256) void cvt_all(CvtArgs a, u16* __restrict__ dst,
                                               const int* __restrict__ flag) {
  const int i = blockIdx.x * 256 + threadIdx.x;
  if (i >= a.start[NSEG]) return;
  int k = 0;
#pragma unroll
  for (int s = 1; s < NSEG; ++s) k += (i >= a.start[s]) ? 1 : 0;
  const int j = i - a.start[k];
  u16 v;
  if (*flag) v = f2b(((const float*)a.src[k])[j]);
  else       v = ((const u16*)a.src[k])[j];
  dst[i] = v;
}

// ---------------- weight transpose ----------------
__global__ __launch_bounds__(256) void transpose_bf16(const u16* __restrict__ src,
                                                      u16* __restrict__ dst, int R, int C) {
  __shared__ u16 tile[32][33];
  const long zo = (long)blockIdx.z * R * C;
  src += zo; dst += zo;
  const int tx = threadIdx.x & 31, ty = threadIdx.x >> 5;
  const int c0 = blockIdx.x * 32, r0 = blockIdx.y * 32;
#pragma unroll
  for (int i = 0; i < 32; i += 8) tile[ty + i][tx] = src[(r0 + ty + i) * C + c0 + tx];
  __syncthreads();
#pragma unroll
  for (int i = 0; i < 32; i += 8) dst[(c0 + ty + i) * R + r0 + tx] = tile[tx][ty + i];
}

// ---------------- embedding + layernorm ----------------
__global__ __launch_bounds__(256) void embed_ln(const int* __restrict__ ids,
    const u16* __restrict__ inW, const u16* __restrict__ inB, const u16* __restrict__ tokE,
    const u16* __restrict__ g, const u16* __restrict__ bb, u16* __restrict__ xb) {
  const int wave = threadIdx.x >> 6, lane = threadIdx.x & 63;
  const int n = blockIdx.x * 4 + wave;
  float idv[6];
#pragma unroll
  for (int f = 0; f < 6; ++f) idv[f] = (float)ids[n * 6 + f];
  float v[8]; float s = 0.f;
#pragma unroll
  for (int j = 0; j < 8; ++j) {
    const int d = j * 64 + lane;
    float a = b2f(inB[d]) + b2f(tokE[d]);
#pragma unroll
    for (int f = 0; f < 6; ++f) a += idv[f] * b2f(inW[f * 512 + d]);
    v[j] = a; s += a;
  }
  s = wred(s);
  const float mu = s * (1.f / 512.f);
  float q = 0.f;
#pragma unroll
  for (int j = 0; j < 8; ++j) { float t = v[j] - mu; q += t * t; }
  q = wred(q);
  const float rstd = rsqrtf(q * (1.f / 512.f) + 1e-12f);
#pragma unroll
  for (int j = 0; j < 8; ++j) {
    const int d = j * 64 + lane;
    xb[n * 512 + d] = f2b(sane((v[j] - mu) * rstd * b2f(g[d]) + b2f(bb[d]), 6e4f));
  }
}

// ---------------- residual add + layernorm ----------------
__global__ __launch_bounds__(256) void add_ln(const u16* __restrict__ xin,
    const u16* __restrict__ add, const u16* __restrict__ g, const u16* __restrict__ bb,
    void* __restrict__ outp, const int* __restrict__ flag, int isfinal) {
  const int wave = threadIdx.x >> 6, lane = threadIdx.x & 63;
  const int n = blockIdx.x * 4 + wave;
  const int base = n * 512 + lane * 8;
  uint4 xa = *(const uint4*)&xin[base];
  uint4 aa = *(const uint4*)&add[base];
  const unsigned* xw = (const unsigned*)&xa;
  const unsigned* aw = (const unsigned*)&aa;
  float v[8]; float s = 0.f;
#pragma unroll
  for (int w = 0; w < 4; ++w) {
    float x0 = b2f((u16)(xw[w] & 0xffff)) + b2f((u16)(aw[w] & 0xffff));
    float x1 = b2f((u16)(xw[w] >> 16)) + b2f((u16)(aw[w] >> 16));
    v[w * 2] = x0; v[w * 2 + 1] = x1; s += x0 + x1;
  }
  s = wred(s);
  const float mu = s * (1.f / 512.f);
  float qs = 0.f;
#pragma unroll
  for (int j = 0; j < 8; ++j) { float t = v[j] - mu; qs += t * t; }
  qs = wred(qs);
  const float rstd = rsqrtf(qs * (1.f / 512.f) + 1e-12f);
  uint4 ga = *(const uint4*)&g[lane * 8];
  uint4 ba = *(const uint4*)&bb[lane * 8];
  const unsigned* gw = (const unsigned*)&ga;
  const unsigned* bw = (const unsigned*)&ba;
  float y[8];
#pragma unroll
  for (int w = 0; w < 4; ++w) {
    y[w * 2]     = sane((v[w * 2] - mu) * rstd * b2f((u16)(gw[w] & 0xffff)) + b2f((u16)(bw[w] & 0xffff)), 6e4f);
    y[w * 2 + 1] = sane((v[w * 2 + 1] - mu) * rstd * b2f((u16)(gw[w] >> 16)) + b2f((u16)(bw[w] >> 16)), 6e4f);
  }
  if (isfinal && *flag) {
    float* of = (float*)outp;
    float4 o0, o1;
    o0.x = y[0]; o0.y = y[1]; o0.z = y[2]; o0.w = y[3];
    o1.x = y[4]; o1.y = y[5]; o1.z = y[6]; o1.w = y[7];
    *(float4*)&of[base] = o0;
    *(float4*)&of[base + 4] = o1;
  } else {
    uint4 o;
    unsigned* ow = (unsigned*)&o;
#pragma unroll
    for (int w = 0; w < 4; ++w)
      ow[w] = (unsigned)f2b(y[w * 2]) | ((unsigned)f2b(y[w * 2 + 1]) << 16);
    *(uint4*)&((u16*)outp)[base] = o;
  }
}

// ---------------- MFMA GEMM: C = A @ BT^T + bias; padded LDS (stride 40) ----------------
enum { EPI_ROW, EPI_GELU, EPI_QKH, EPI_VT };

template <int EPI>
__global__ __launch_bounds__(256)
void gemm_bt(const u16* __restrict__ A, const u16* __restrict__ BT,
             const u16* __restrict__ bias, u16* __restrict__ out, int K, int ldo) {
  __shared__ alignas(16) u16 sA[128 * 40];
  __shared__ alignas(16) u16 sB[128 * 40];
  const int tid = threadIdx.x;
  const int wave = tid >> 6, lane = tid & 63;
  const int quad = lane >> 4, li = lane & 15;
  const int m0 = blockIdx.x * 128, n0 = blockIdx.y * 128;
  const u16* Ab = A + m0 * K;
  const u16* Bb = BT + n0 * K;
  const int wm = wave >> 1, wn = wave & 1;
  const int r0 = tid >> 2, kc0 = tid & 3;
  f32x4 acc[4][4] = {};
  for (int kt = 0; kt < K; kt += 32) {
    __syncthreads();
    uint4 a0 = *(const uint4*)(Ab + r0 * K + kt + kc0 * 8);
    uint4 a1 = *(const uint4*)(Ab + (r0 + 64) * K + kt + kc0 * 8);
    uint4 b0 = *(const uint4*)(Bb + r0 * K + kt + kc0 * 8);
    uint4 b1 = *(const uint4*)(Bb + (r0 + 64) * K + kt + kc0 * 8);
    *(uint4*)&sA[r0 * 40 + kc0 * 8] = a0;
    *(uint4*)&sA[(r0 + 64) * 40 + kc0 * 8] = a1;
    *(uint4*)&sB[r0 * 40 + kc0 * 8] = b0;
    *(uint4*)&sB[(r0 + 64) * 40 + kc0 * 8] = b1;
    __syncthreads();
    bf16x8 aF[4], bF[4];
#pragma unroll
    for (int mt = 0; mt < 4; ++mt)
      aF[mt] = *(const bf16x8*)&sA[(wm * 64 + mt * 16 + li) * 40 + quad * 8];
#pragma unroll
    for (int nt = 0; nt < 4; ++nt)
      bF[nt] = *(const bf16x8*)&sB[(wn * 64 + nt * 16 + li) * 40 + quad * 8];
#pragma unroll
    for (int mt = 0; mt < 4; ++mt)
#pragma unroll
      for (int nt = 0; nt < 4; ++nt)
        acc[mt][nt] = __builtin_amdgcn_mfma_f32_16x16x32_bf16(aF[mt], bF[nt], acc[mt][nt], 0, 0, 0);
  }
  if constexpr (EPI == EPI_VT) {
    // transpose through LDS for coalesced [bh][dh][s] stores
    __shared__ alignas(16) u16 sE[128 * 136];
#pragma unroll
    for (int mt = 0; mt < 4; ++mt)
#pragma unroll
      for (int nt = 0; nt < 4; ++nt)
#pragma unroll
        for (int r = 0; r < 4; ++r) {
          const int ml = wm * 64 + mt * 16 + quad * 4 + r;
          const int nl = wn * 64 + nt * 16 + li;
          float v = sane(acc[mt][nt][r] + b2f(bias[n0 + nl]), 6e4f);
          sE[nl * 136 + ml] = f2b(v);
        }
    __syncthreads();
    const int bht = (m0 >> 8) * 4 + (n0 >> 7);
    const int s0 = m0 & 255;
    const int dh = tid >> 1, half = tid & 1;
    u16* orow = out + ((size_t)bht * 128 + dh) * 256 + s0 + half * 64;
    const u16* srow = &sE[dh * 136 + half * 64];
#pragma unroll
    for (int i = 0; i < 8; ++i)
      *(uint4*)&orow[i * 8] = *(const uint4*)&srow[i * 8];
  } else {
#pragma unroll
    for (int mt = 0; mt < 4; ++mt) {
#pragma unroll
      for (int nt = 0; nt < 4; ++nt) {
#pragma unroll
        for (int r = 0; r < 4; ++r) {
          const int m = m0 + wm * 64 + mt * 16 + quad * 4 + r;
          const int n = n0 + wn * 64 + nt * 16 + li;
          float v = sane(acc[mt][nt][r] + b2f(bias[n]), 6e4f);
          if constexpr (EPI == EPI_GELU) v = 0.5f * v * (1.0f + erff(v * 0.70710678118654752f));
          if constexpr (EPI == EPI_ROW || EPI == EPI_GELU) {
            out[m * ldo + n] = f2b(v);
          } else { // EPI_QKH -> [bh][s][dh]
            out[(((m >> 8) * 4 + (n >> 7)) * 256 + (m & 255)) * 128 + (n & 127)] = f2b(v);
          }
        }
      }
    }
  }
}

// ---------------- fused attention ----------------
// grid = dim3(4, 512): blockIdx.x = lt (fast -> same-bh blocks adjacent for K/V L2 reuse).
// LDS layout (81920 B total = 2 blocks/CU):
//   sKV 16384 B : K chunk [64 rows][256 B] XOR-swz   |  V chunk [128 rows][128 B] XOR-swz
//   sPB 32768 B : bands sT3 [64][128B]swz @0, sT2 @8192  |  later P [64][512B]swz
//   sDE 32768 B : de tile rows [rb, rb+128) [128 rows][256 B] XOR-swz | later ctx-out tile
// XOR swizzle: byte ^= (row&7)<<4  (write and read sides identical).
// ALL register staging is SINGLE-buffered (kreg[4]/dreg[8]/vreg[4]): ds_write captures
// VGPR sources at issue, and per-wave in-order issue means the next chunk's global_load
// (issued right after the ds_write) cannot clobber them. This is what keeps arch-VGPR
// pressure under 128 (round-2's dreg[2][8] double-buffer spilled ~180KB/block to scratch:
// WRITE_SIZE 172->547 MB).
__global__ __launch_bounds__(256, 2)
void attn_kernel(const u16* __restrict__ qb, const u16* __restrict__ kb,
                 const u16* __restrict__ vtb, const u16* __restrict__ de,
                 const u16* __restrict__ mask, u16* __restrict__ ctx) {
  __shared__ alignas(16) char sKV[16384];
  __shared__ alignas(16) char sPB[32768];
  __shared__ alignas(16) char sDE[32768];
  const int tid = threadIdx.x;
  const int wave = tid >> 6, lane = tid & 63, quad = lane >> 4, li = lane & 15;
  const int lt = blockIdx.x;
  const int bh = blockIdx.y;
  const int b = bh >> 2, h = bh & 3;
  const int l0 = lt * 64;
  const u16* Qg = qb + (size_t)bh * 256 * 128;
  const u16* Kg = kb + (size_t)bh * 256 * 128;
  const u16* Vg = vtb + (size_t)bh * 128 * 256;
  const float scale = 0.08838834764831845f;

  // ---- prefetch K chunk 0 + de tile 0 into regs (single buffers) ----
  const int krow = tid >> 2, kq4 = tid & 3;
  const int drw = tid >> 4, dcl = tid & 15;  // de staging: 16 threads/row
  uint4 kreg[4];
  uint4 dreg[8];
#pragma unroll
  for (int i = 0; i < 4; ++i)
    kreg[i] = *(const uint4*)&Kg[krow * 128 + kq4 * 8 + i * 32];
  {
    const int rb0 = l0 + 192;  // c = 0
#pragma unroll
    for (int i = 0; i < 8; ++i) {
      const int rr = i * 16 + drw;
      const int g = min(rb0 + rr, 510);
      dreg[i] = *(const uint4*)&de[g * 128 + dcl * 8];
    }
  }

  bf16x8 aQ[4];
#pragma unroll
  for (int kt = 0; kt < 4; ++kt)
    aQ[kt] = *(const bf16x8*)&Qg[(l0 + wave * 16 + li) * 128 + kt * 32 + quad * 8];

  f32x4 sc[16] = {};
#pragma unroll
  for (int c = 0; c < 4; ++c) {
    const int rb = l0 - c * 64 + 192;  // de tile base row for this chunk
    if (c > 0) bar_lgkm();  // prev chunk's LDS readers fully drained
    // write staged K chunk [64][256B] swz (ds_write captures regs at issue)
#pragma unroll
    for (int i = 0; i < 4; ++i)
      *(uint4*)&sKV[(krow * 256 + kq4 * 16 + i * 64) ^ ((krow & 7) << 4)] = kreg[i];
    // write staged de tile [128][256B] swz
#pragma unroll
    for (int i = 0; i < 8; ++i) {
      const int rr = i * 16 + drw;
      *(uint4*)&sDE[(rr * 256 + dcl * 16) ^ ((rr & 7) << 4)] = dreg[i];
    }
    // issue next chunk's global loads into the SAME regs (WAR vs ds_write is safe;
    // loads stay in flight across the raw barriers, vmcnt waited at next ds_write)
    if (c < 3) {
#pragma unroll
      for (int i = 0; i < 4; ++i)
        kreg[i] = *(const uint4*)&Kg[((c + 1) * 64 + krow) * 128 + kq4 * 8 + i * 32];
      const int rbn = rb - 64;
#pragma unroll
      for (int i = 0; i < 8; ++i) {
        const int rr = i * 16 + drw;
        const int g = min(rbn + rr, 510);
        dreg[i] = *(const uint4*)&de[g * 128 + dcl * 8];
      }
    }
    bar_lgkm();
    __builtin_amdgcn_s_setprio(1);
    // QK^T
#pragma unroll
    for (int kt = 0; kt < 4; ++kt) {
#pragma unroll
      for (int nt = 0; nt < 4; ++nt) {
        const int row = nt * 16 + li;
        bf16x8 bK = *(const bf16x8*)&sKV[(row * 256 + kt * 64 + quad * 16) ^ ((row & 7) << 4)];
        sc[c * 4 + nt] = __builtin_amdgcn_mfma_f32_16x16x32_bf16(aQ[kt], bK, sc[c * 4 + nt], 0, 0, 0);
      }
    }
    // term3: G3[r][p] = k[r]·de[p]; banded to sT3[rL][j]
    {
      f32x4 g3[5] = {};
      const int Ab = l0 - (c * 64 + wave * 16) + 240;
#pragma unroll
      for (int kt = 0; kt < 4; ++kt) {
        const int arow = wave * 16 + li;
        bf16x8 aK = *(const bf16x8*)&sKV[(arow * 256 + kt * 64 + quad * 16) ^ ((arow & 7) << 4)];
#pragma unroll
        for (int pt = 0; pt < 5; ++pt) {
          const int prow = min(Ab + pt * 16 + li, 510);
          const int rr = prow - rb;
          bf16x8 bD = *(const bf16x8*)&sDE[(rr * 256 + kt * 64 + quad * 16) ^ ((rr & 7) << 4)];
          g3[pt] = __builtin_amdgcn_mfma_f32_16x16x32_bf16(aK, bD, g3[pt], 0, 0, 0);
        }
      }
#pragma unroll
      for (int pt = 0; pt < 5; ++pt)
#pragma unroll
        for (int r = 0; r < 4; ++r) {
          const int rL = wave * 16 + quad * 4 + r;
          const int j = pt * 16 + li + quad * 4 + r - 15;
          if ((unsigned)j < 64u)
            *(u16*)&sPB[(rL * 128 + j * 2) ^ ((rL & 7) << 4)] = f2b(g3[pt][r]);
        }
    }
    // term2: G2[l][p] = q[l]·de[p]; banded to sT2[lL][rcol]
    {
      f32x4 g2[5] = {};
      const int A2 = rb + wave * 16;
#pragma unroll
      for (int kt = 0; kt < 4; ++kt) {
#pragma unroll
        for (int pt = 0; pt < 5; ++pt) {
          const int prow = min(A2 + pt * 16 + li, 510);
          const int rr = prow - rb;
          bf16x8 bD = *(const bf16x8*)&sDE[(rr * 256 + kt * 64 + quad * 16) ^ ((rr & 7) << 4)];
          g2[pt] = __builtin_amdgcn_mfma_f32_16x16x32_bf16(aQ[kt], bD, g2[pt], 0, 0, 0);
        }
      }
      __builtin_amdgcn_s_setprio(0);
#pragma unroll
      for (int pt = 0; pt < 5; ++pt)
#pragma unroll
        for (int r = 0; r < 4; ++r) {
          const int lL = wave * 16 + quad * 4 + r;
          const int rcol = quad * 4 + r + 63 - pt * 16 - li;
          if ((unsigned)rcol < 64u)
            *(u16*)&sPB[8192 + ((lL * 128 + rcol * 2) ^ ((lL & 7) << 4))] = f2b(g2[pt][r]);
        }
    }
    bar_lgkm();  // band writes visible
#pragma unroll
    for (int t2 = 0; t2 < 4; ++t2)
#pragma unroll
      for (int r = 0; r < 4; ++r) {
        const int myl = wave * 16 + quad * 4 + r;
        const int r3 = t2 * 16 + li;
        float v3 = sane(b2f(*(const u16*)&sPB[(r3 * 128 + myl * 2) ^ ((r3 & 7) << 4)]), 1e4f);
        float v2 = sane(b2f(*(const u16*)&sPB[8192 + ((myl * 128 + r3 * 2) ^ ((myl & 7) << 4))]), 1e4f);
        sc[c * 4 + t2][r] += v3 + v2;
      }
  }

  // ---- issue V chunk 0 prefetch; overlaps mask load + softmax VALU ----
  const int vrow = tid >> 1, vhalf = tid & 1;
  uint4 vreg[4];
#pragma unroll
  for (int i = 0; i < 4; ++i)
    vreg[i] = *(const uint4*)&Vg[vrow * 256 + vhalf * 32 + i * 8];

  float mbv[16];
#pragma unroll
  for (int t = 0; t < 16; ++t)
    mbv[t] = (1.0f - b2f(mask[b * 256 + t * 16 + li])) * -1e9f;

  // logits + softmax
#pragma unroll
  for (int t = 0; t < 16; ++t)
#pragma unroll
    for (int r = 0; r < 4; ++r) sc[t][r] = sane(sc[t][r] * scale + mbv[t], 2e9f);
#pragma unroll
  for (int r = 0; r < 4; ++r) {
    float mx = -3.0e38f;
#pragma unroll
    for (int t = 0; t < 16; ++t) mx = fmaxf(mx, sc[t][r]);
#pragma unroll
    for (int m = 1; m < 16; m <<= 1) mx = fmaxf(mx, __shfl_xor(mx, m, 64));
    float s = 0.f;
#pragma unroll
    for (int t = 0; t < 16; ++t) { float e = __expf(sc[t][r] - mx); sc[t][r] = e; s += e; }
#pragma unroll
    for (int m = 1; m < 16; m <<= 1) s += __shfl_xor(s, m, 64);
    const float inv = 1.f / s;
#pragma unroll
    for (int t = 0; t < 16; ++t) sc[t][r] *= inv;
  }

  bar_lgkm();  // band readers done; reuse sPB as P [64][512B] swz
#pragma unroll
  for (int t = 0; t < 16; ++t)
#pragma unroll
    for (int r = 0; r < 4; ++r) {
      const int row = wave * 16 + quad * 4 + r;
      *(u16*)&sPB[(row * 512 + (t * 16 + li) * 2) ^ ((row & 7) << 4)] = f2b(sc[t][r]);
    }

  // PV: V chunks [128 rows][128 B] swz
  f32x4 ct[8] = {};
#pragma unroll
  for (int c = 0; c < 4; ++c) {
    if (c > 0) bar_lgkm();  // prev chunk's PV reads drained
#pragma unroll
    for (int i = 0; i < 4; ++i)
      *(uint4*)&sKV[(vrow * 128 + vhalf * 64 + i * 16) ^ ((vrow & 7) << 4)] = vreg[i];
    if (c < 3) {
#pragma unroll
      for (int i = 0; i < 4; ++i)
        vreg[i] = *(const uint4*)&Vg[vrow * 256 + (c + 1) * 64 + vhalf * 32 + i * 8];
    }
    bar_lgkm();  // covers P writes (c==0) + V chunk writes
    __builtin_amdgcn_s_setprio(1);
#pragma unroll
    for (int ks = 0; ks < 2; ++ks) {
      const int prow = wave * 16 + li;
      bf16x8 aF = *(const bf16x8*)&sPB[(prow * 512 + c * 128 + ks * 64 + quad * 16) ^ ((prow & 7) << 4)];
#pragma unroll
      for (int nt = 0; nt < 8; ++nt) {
        const int row = nt * 16 + li;
        bf16x8 bV = *(const bf16x8*)&sKV[(row * 128 + ks * 64 + quad * 16) ^ ((row & 7) << 4)];
        ct[nt] = __builtin_amdgcn_mfma_f32_16x16x32_bf16(aF, bV, ct[nt], 0, 0, 0);
      }
    }
    __builtin_amdgcn_s_setprio(0);
  }

  // ctx epilogue: write [64 rows][256B] swz tile into sDE (free since QK phase).
  // Writer wave == reader wave for each row => no barrier needed, lgkmcnt only.
#pragma unroll
  for (int nt = 0; nt < 8; ++nt)
#pragma unroll
    for (int r = 0; r < 4; ++r) {
      const int row = wave * 16 + quad * 4 + r;
      *(u16*)&sDE[(row * 256 + (nt * 16 + li) * 2) ^ ((row & 7) << 4)] = f2b(sane(ct[nt][r], 1e4f));
    }
  asm volatile("s_waitcnt lgkmcnt(0)" ::: "memory");
  __builtin_amdgcn_sched_barrier(0);
  {  // coalesced ctx store: 4 uint4 = 32 elems/thread (reads own wave's rows)
    const int row = tid >> 2, seg = tid & 3;
    u16* orow = ctx + ((size_t)(b * 256 + l0 + row)) * 512 + h * 128 + seg * 32;
#pragma unroll
    for (int i = 0; i < 4; ++i) {
      uint4 v = *(const uint4*)&sDE[(row * 256 + seg * 64 + i * 16) ^ ((row & 7) << 4)];
      *(uint4*)&orow[i * 8] = v;
    }
  }
}

// ---------------- orchestration ----------------
extern "C" void kernel_launch(void* const* d_in, const int* in_sizes, int n_in,
                              void* d_out, int out_size, void* d_ws, size_t ws_size,
                              hipStream_t stream) {
  (void)in_sizes; (void)n_in; (void)out_size; (void)ws_size;
  const int* ids = (const int*)d_in[0];

  static const int ns[NSEG] = {
      32768, 3072, 512, 512, 512, 512, 65408,
      1048576, 2048, 1048576, 2048, 1048576, 2048, 1048576, 2048,
      2048, 2048, 262144, 512, 262144, 2048, 2048, 2048
  };
  CvtArgs ca;
  int st[NSEG + 1];
  st[0] = 0;
  for (int k = 0; k < NSEG; ++k) { ca.src[k] = d_in[k + 1]; st[k + 1] = st[k] + ns[k]; }
  for (int k = 0; k <= NSEG; ++k) ca.start[k] = st[k];
  const int total = st[NSEG];

  char* W = (char*)d_ws;
  size_t off = 0;
  auto alloc = [&](size_t bytes) { void* p = W + off; off += (bytes + 255) & ~(size_t)255; return p; };
  u16* canon = (u16*)alloc((size_t)total * 2);
  int* flag  = (int*)alloc(256);
  const size_t ND = (size_t)32768 * 512;
  u16* xb   = (u16*)alloc(ND * 2);
  u16* qbf  = (u16*)alloc(ND * 2);
  u16* kbf  = (u16*)alloc(ND * 2);
  u16* vtb  = (u16*)alloc(ND * 2);
  u16* wqT  = (u16*)alloc((size_t)4 * 512 * 512 * 2);
  u16* wkT  = (u16*)alloc((size_t)4 * 512 * 512 * 2);
  u16* wvT  = (u16*)alloc((size_t)4 * 512 * 512 * 2);
  u16* woT  = (u16*)alloc((size_t)4 * 512 * 512 * 2);
  u16* wiT  = (u16*)alloc((size_t)4 * 512 * 128 * 2);
  u16* wo2T = (u16*)alloc((size_t)4 * 128 * 512 * 2);
  u16* ctxb = (u16*)d_out;

  const u16* mask = canon + st[0];
  const u16* inW  = canon + st[1];
  const u16* inB  = canon + st[2];
  const u16* tokE = canon + st[3];
  const u16* eg   = canon + st[4];
  const u16* ebb  = canon + st[5];
  const u16* de   = canon + st[6];
  const u16* Wq   = canon + st[7];
  const u16* bq   = canon + st[8];
  const u16* Wk   = canon + st[9];
  const u16* bk   = canon + st[10];
  const u16* Wv   = canon + st[11];
  const u16* bv   = canon + st[12];
  const u16* Wo   = canon + st[13];
  const u16* bo   = canon + st[14];
  const u16* l1g  = canon + st[15];
  const u16* l1b  = canon + st[16];
  const u16* Wi   = canon + st[17];
  const u16* bi   = canon + st[18];
  const u16* Wo2  = canon + st[19];
  const u16* bo2  = canon + st[20];
  const u16* l2g  = canon + st[21];
  const u16* l2b  = canon + st[22];

  dim3 B256(256);
  detect_dtype<<<1, 1, 0, stream>>>((const unsigned*)d_in[5], flag);
  cvt_all<<<(total + 255) / 256, B256, 0, stream>>>(ca, canon, flag);
  transpose_bf16<<<dim3(16, 16, 4), B256, 0, stream>>>(Wq, wqT, 512, 512);
  transpose_bf16<<<dim3(16, 16, 4), B256, 0, stream>>>(Wk, wkT, 512, 512);
  transpose_bf16<<<dim3(16, 16, 4), B256, 0, stream>>>(Wv, wvT, 512, 512);
  transpose_bf16<<<dim3(16, 16, 4), B256, 0, stream>>>(Wo, woT, 512, 512);
  transpose_bf16<<<dim3(4, 16, 4), B256, 0, stream>>>(Wi, wiT, 512, 128);
  transpose_bf16<<<dim3(16, 4, 4), B256, 0, stream>>>(Wo2, wo2T, 128, 512);
  embed_ln<<<8192, B256, 0, stream>>>(ids, inW, inB, tokE, eg, ebb, xb);

  for (int l = 0; l < 4; ++l) {
    gemm_bt<EPI_QKH><<<dim3(256, 4), B256, 0, stream>>>(xb, wqT + l * 512 * 512, bq + l * 512, qbf, 512, 0);
    gemm_bt<EPI_QKH><<<dim3(256, 4), B256, 0, stream>>>(xb, wkT + l * 512 * 512, bk + l * 512, kbf, 512, 0);
    gemm_bt<EPI_VT><<<dim3(256, 4), B256, 0, stream>>>(xb, wvT + l * 512 * 512, bv + l * 512, vtb, 512, 0);
    attn_kernel<<<dim3(4, 512), B256, 0, stream>>>(qbf, kbf, vtb, de, mask, ctxb);
    gemm_bt<EPI_ROW><<<dim3(256, 4), B256, 0, stream>>>(ctxb, woT + l * 512 * 512, bo + l * 512, qbf, 512, 512);
    add_ln<<<8192, B256, 0, stream>>>(xb, qbf, l1g + l * 512, l1b + l * 512, xb, flag, 0);
    gemm_bt<EPI_GELU><<<dim3(256, 1), B256, 0, stream>>>(xb, wiT + l * 512 * 128, bi + l * 128, kbf, 512, 128);
    gemm_bt<EPI_ROW><<<dim3(256, 4), B256, 0, stream>>>(kbf, wo2T + l * 128 * 512, bo2 + l * 512, vtb, 128, 512);
    add_ln<<<8192, B256, 0, stream>>>(xb, vtb, l2g + l * 512, l2b + l * 512,
                                      (l == 3) ? d_out : (void*)xb, flag, (l == 3) ? 1 : 0);
  }
}

// Round 4
// 2065.648 us; speedup vs baseline: 1.0673x; 1.0023x over previous
//
#include <hip/hip_runtime.h>

typedef unsigned short u16;
typedef __bf16 bf16x8 __attribute__((ext_vector_type(8)));
typedef float f32x4 __attribute__((ext_vector_type(4)));

__device__ __forceinline__ float b2f(u16 u) { return __uint_as_float(((unsigned)u) << 16); }
__device__ __forceinline__ u16 f2b(float f) {
  unsigned i = __float_as_uint(f);
  return (u16)((i + 0x7FFFu + ((i >> 16) & 1u)) >> 16);
}
__device__ __forceinline__ float sane(float x, float lim) {
  float y = fminf(fmaxf(x, -lim), lim);
  return (y != y) ? 0.0f : y;
}
__device__ __forceinline__ float wred(float x) {
#pragma unroll
  for (int m = 1; m < 64; m <<= 1) x += __shfl_xor(x, m, 64);
  return x;
}

// raw barrier that waits LDS ops only (keeps global-load prefetch in flight,
// unlike __syncthreads which drains vmcnt(0))
__device__ __forceinline__ void bar_lgkm() {
  asm volatile("s_waitcnt lgkmcnt(0)" ::: "memory");
  __builtin_amdgcn_s_barrier();
  asm volatile("" ::: "memory");
}

// ---------------- dtype detect ----------------
__global__ void detect_dtype(const unsigned* __restrict__ g_ones, int* __restrict__ flag) {
  *flag = (g_ones[0] == 0x3F800000u) ? 1 : 0;
}

// ---------------- batched convert: all float inputs -> canonical bf16 ----------------
#define NSEG 23
struct CvtArgs {
  const void* src[NSEG];
  int start[NSEG + 1];
};
__global__ __launch_bounds__(256) void cvt_all(CvtArgs a, u16* __restrict__ dst,
                                               const int* __restrict__ flag) {
  const int i = blockIdx.x * 256 + threadIdx.x;
  if (i >= a.start[NSEG]) return;
  int k = 0;
#pragma unroll
  for (int s = 1; s < NSEG; ++s) k += (i >= a.start[s]) ? 1 : 0;
  const int j = i - a.start[k];
  u16 v;
  if (*flag) v = f2b(((const float*)a.src[k])[j]);
  else       v = ((const u16*)a.src[k])[j];
  dst[i] = v;
}

// ---------------- weight transpose ----------------
__global__ __launch_bounds__(256) void transpose_bf16(const u16* __restrict__ src,
                                                      u16* __restrict__ dst, int R, int C) {
  __shared__ u16 tile[32][33];
  const long zo = (long)blockIdx.z * R * C;
  src += zo; dst += zo;
  const int tx = threadIdx.x & 31, ty = threadIdx.x >> 5;
  const int c0 = blockIdx.x * 32, r0 = blockIdx.y * 32;
#pragma unroll
  for (int i = 0; i < 32; i += 8) tile[ty + i][tx] = src[(r0 + ty + i) * C + c0 + tx];
  __syncthreads();
#pragma unroll
  for (int i = 0; i < 32; i += 8) dst[(c0 + ty + i) * R + r0 + tx] = tile[tx][ty + i];
}

// ---------------- embedding + layernorm ----------------
__global__ __launch_bounds__(256) void embed_ln(const int* __restrict__ ids,
    const u16* __restrict__ inW, const u16* __restrict__ inB, const u16* __restrict__ tokE,
    const u16* __restrict__ g, const u16* __restrict__ bb, u16* __restrict__ xb) {
  const int wave = threadIdx.x >> 6, lane = threadIdx.x & 63;
  const int n = blockIdx.x * 4 + wave;
  float idv[6];
#pragma unroll
  for (int f = 0; f < 6; ++f) idv[f] = (float)ids[n * 6 + f];
  float v[8]; float s = 0.f;
#pragma unroll
  for (int j = 0; j < 8; ++j) {
    const int d = j * 64 + lane;
    float a = b2f(inB[d]) + b2f(tokE[d]);
#pragma unroll
    for (int f = 0; f < 6; ++f) a += idv[f] * b2f(inW[f * 512 + d]);
    v[j] = a; s += a;
  }
  s = wred(s);
  const float mu = s * (1.f / 512.f);
  float q = 0.f;
#pragma unroll
  for (int j = 0; j < 8; ++j) { float t = v[j] - mu; q += t * t; }
  q = wred(q);
  const float rstd = rsqrtf(q * (1.f / 512.f) + 1e-12f);
#pragma unroll
  for (int j = 0; j < 8; ++j) {
    const int d = j * 64 + lane;
    xb[n * 512 + d] = f2b(sane((v[j] - mu) * rstd * b2f(g[d]) + b2f(bb[d]), 6e4f));
  }
}

// ---------------- residual add + layernorm ----------------
__global__ __launch_bounds__(256) void add_ln(const u16* __restrict__ xin,
    const u16* __restrict__ add, const u16* __restrict__ g, const u16* __restrict__ bb,
    void* __restrict__ outp, const int* __restrict__ flag, int isfinal) {
  const int wave = threadIdx.x >> 6, lane = threadIdx.x & 63;
  const int n = blockIdx.x * 4 + wave;
  const int base = n * 512 + lane * 8;
  uint4 xa = *(const uint4*)&xin[base];
  uint4 aa = *(const uint4*)&add[base];
  const unsigned* xw = (const unsigned*)&xa;
  const unsigned* aw = (const unsigned*)&aa;
  float v[8]; float s = 0.f;
#pragma unroll
  for (int w = 0; w < 4; ++w) {
    float x0 = b2f((u16)(xw[w] & 0xffff)) + b2f((u16)(aw[w] & 0xffff));
    float x1 = b2f((u16)(xw[w] >> 16)) + b2f((u16)(aw[w] >> 16));
    v[w * 2] = x0; v[w * 2 + 1] = x1; s += x0 + x1;
  }
  s = wred(s);
  const float mu = s * (1.f / 512.f);
  float qs = 0.f;
#pragma unroll
  for (int j = 0; j < 8; ++j) { float t = v[j] - mu; qs += t * t; }
  qs = wred(qs);
  const float rstd = rsqrtf(qs * (1.f / 512.f) + 1e-12f);
  uint4 ga = *(const uint4*)&g[lane * 8];
  uint4 ba = *(const uint4*)&bb[lane * 8];
  const unsigned* gw = (const unsigned*)&ga;
  const unsigned* bw = (const unsigned*)&ba;
  float y[8];
#pragma unroll
  for (int w = 0; w < 4; ++w) {
    y[w * 2]     = sane((v[w * 2] - mu) * rstd * b2f((u16)(gw[w] & 0xffff)) + b2f((u16)(bw[w] & 0xffff)), 6e4f);
    y[w * 2 + 1] = sane((v[w * 2 + 1] - mu) * rstd * b2f((u16)(gw[w] >> 16)) + b2f((u16)(bw[w] >> 16)), 6e4f);
  }
  if (isfinal && *flag) {
    float* of = (float*)outp;
    float4 o0, o1;
    o0.x = y[0]; o0.y = y[1]; o0.z = y[2]; o0.w = y[3];
    o1.x = y[4]; o1.y = y[5]; o1.z = y[6]; o1.w = y[7];
    *(float4*)&of[base] = o0;
    *(float4*)&of[base + 4] = o1;
  } else {
    uint4 o;
    unsigned* ow = (unsigned*)&o;
#pragma unroll
    for (int w = 0; w < 4; ++w)
      ow[w] = (unsigned)f2b(y[w * 2]) | ((unsigned)f2b(y[w * 2 + 1]) << 16);
    *(uint4*)&((u16*)outp)[base] = o;
  }
}

// ---------------- MFMA GEMM: C = A @ BT^T + bias ----------------
// global_load_lds(16B) staging, BK=64, linear LDS dest + pre-swizzled global source
// column (chunk ^= row&7) so ds_read_b128 fragment reads are conflict-spread with the
// matching XOR on the read side (T2 both-sides-or-neither rule).
// LDS: one 32KB block; sA=[0,16KB) sB=[16KB,32KB), each [128 rows][64 cols bf16 =128B].
// EPI_VT overlays its 32KB transpose tile on the same block after the K-loop.
enum { EPI_ROW, EPI_GELU, EPI_QKH, EPI_VT };

typedef __attribute__((address_space(1))) const char gld_g;
typedef __attribute__((address_space(3))) char gld_l;

template <int EPI>
__global__ __launch_bounds__(256)
void gemm_bt(const u16* __restrict__ A, const u16* __restrict__ BT,
             const u16* __restrict__ bias, u16* __restrict__ out, int K, int ldo) {
  __shared__ alignas(16) u16 sT[2 * 128 * 64];
  u16* sA = sT;
  u16* sB = sT + 128 * 64;
  const int tid = threadIdx.x;
  const int wave = tid >> 6, lane = tid & 63;
  const int quad = lane >> 4, li = lane & 15;
  const int m0 = blockIdx.x * 128, n0 = blockIdx.y * 128;
  const u16* Ab = A + (size_t)m0 * K;
  const u16* Bb = BT + (size_t)n0 * K;
  const int wm = wave >> 1, wn = wave & 1;
  const int lrow = lane >> 3;           // 0..7 : row within 8-row stage group
  const int lchk = (lane & 7) ^ lrow;   // pre-swizzled 16B chunk index
  f32x4 acc[4][4] = {};
  for (int kt = 0; kt < K; kt += 64) {
    if (kt) __syncthreads();  // prev iteration's ds_reads done before overwrite
#pragma unroll
    for (int i = 0; i < 4; ++i) {
      const int r = wave * 32 + i * 8 + lrow;  // global row this lane fetches
      __builtin_amdgcn_global_load_lds(
          (gld_g*)(Ab + (size_t)r * K + kt + lchk * 8),
          (gld_l*)&sA[(wave * 32 + i * 8) * 64], 16, 0, 0);
      __builtin_amdgcn_global_load_lds(
          (gld_g*)(Bb + (size_t)r * K + kt + lchk * 8),
          (gld_l*)&sB[(wave * 32 + i * 8) * 64], 16, 0, 0);
    }
    asm volatile("s_waitcnt vmcnt(0)" ::: "memory");
    __syncthreads();
#pragma unroll
    for (int h = 0; h < 2; ++h) {
      bf16x8 aF[4], bF[4];
#pragma unroll
      for (int mt = 0; mt < 4; ++mt) {
        const int r = wm * 64 + mt * 16 + li;
        aF[mt] = *(const bf16x8*)&sA[r * 64 + ((h * 32 + quad * 8) ^ ((r & 7) << 3))];
      }
#pragma unroll
      for (int nt = 0; nt < 4; ++nt) {
        const int r = wn * 64 + nt * 16 + li;
        bF[nt] = *(const bf16x8*)&sB[r * 64 + ((h * 32 + quad * 8) ^ ((r & 7) << 3))];
      }
#pragma unroll
      for (int mt = 0; mt < 4; ++mt)
#pragma unroll
        for (int nt = 0; nt < 4; ++nt)
          acc[mt][nt] = __builtin_amdgcn_mfma_f32_16x16x32_bf16(aF[mt], bF[nt], acc[mt][nt], 0, 0, 0);
    }
  }
  if constexpr (EPI == EPI_VT) {
    // transpose through LDS (overlaid on staging buffers) for coalesced [bh][dh][s] stores
    __syncthreads();  // all waves' final ds_reads done before overlay
#pragma unroll
    for (int mt = 0; mt < 4; ++mt)
#pragma unroll
      for (int nt = 0; nt < 4; ++nt)
#pragma unroll
        for (int r = 0; r < 4; ++r) {
          const int ml = wm * 64 + mt * 16 + quad * 4 + r;
          const int nl = wn * 64 + nt * 16 + li;
          float v = sane(acc[mt][nt][r] + b2f(bias[n0 + nl]), 6e4f);
          sT[nl * 128 + (ml ^ ((nl & 7) << 3))] = f2b(v);
        }
    __syncthreads();
    const int bht = (m0 >> 8) * 4 + (n0 >> 7);
    const int s0 = m0 & 255;
    const int dh = tid >> 1, half = tid & 1;
    u16* orow = out + ((size_t)bht * 128 + dh) * 256 + s0 + half * 64;
#pragma unroll
    for (int i = 0; i < 8; ++i) {
      const int idx = dh * 128 + ((half * 64 + i * 8) ^ ((dh & 7) << 3));
      *(uint4*)&orow[i * 8] = *(const uint4*)&sT[idx];
    }
  } else {
#pragma unroll
    for (int mt = 0; mt < 4; ++mt) {
#pragma unroll
      for (int nt = 0; nt < 4; ++nt) {
#pragma unroll
        for (int r = 0; r < 4; ++r) {
          const int m = m0 + wm * 64 + mt * 16 + quad * 4 + r;
          const int n = n0 + wn * 64 + nt * 16 + li;
          float v = sane(acc[mt][nt][r] + b2f(bias[n]), 6e4f);
          if constexpr (EPI == EPI_GELU) v = 0.5f * v * (1.0f + erff(v * 0.70710678118654752f));
          if constexpr (EPI == EPI_ROW || EPI == EPI_GELU) {
            out[m * ldo + n] = f2b(v);
          } else { // EPI_QKH -> [bh][s][dh]
            out[(((m >> 8) * 4 + (n >> 7)) * 256 + (m & 255)) * 128 + (n & 127)] = f2b(v);
          }
        }
      }
    }
  }
}

// ---------------- fused attention: one block per (lt, bh); reg-prefetched staging ----------------
// (round-1 version, verbatim: 256 us, VGPR 84, no scratch. The de-in-LDS redesigns of
// rounds 2-3 spilled ~300MB to scratch and were slower; reverted.)
// grid = dim3(4, 512): blockIdx.x = lt (fast, so 4 blocks of same bh are dispatch-adjacent
// and share K/V through L2), blockIdx.y = bh.
__global__ __launch_bounds__(256, 3)
void attn_kernel(const u16* __restrict__ qb, const u16* __restrict__ kb,
                 const u16* __restrict__ vtb, const u16* __restrict__ de,
                 const u16* __restrict__ mask, u16* __restrict__ ctx) {
  __shared__ alignas(16) u16 sKV[9216];
  __shared__ alignas(16) u16 sP[16896];
  u16* sT3 = sP;
  u16* sT2 = sP + 4224;
  const int tid = threadIdx.x;
  const int wave = tid >> 6, lane = tid & 63, quad = lane >> 4, li = lane & 15;
  const int lt = blockIdx.x;
  const int bh = blockIdx.y;
  const int b = bh >> 2, h = bh & 3;
  const int l0 = lt * 64;
  const u16* Qg = qb + (size_t)bh * 256 * 128;
  const u16* Kg = kb + (size_t)bh * 256 * 128;
  const u16* Vg = vtb + (size_t)bh * 128 * 256;
  const float scale = 0.08838834764831845f;

  // ---- issue K chunk 0 prefetch first (deepest on the critical path) ----
  const int krow = tid >> 2, kq4 = tid & 3;
  uint4 kreg[2][4];
#pragma unroll
  for (int i = 0; i < 4; ++i)
    kreg[0][i] = *(const uint4*)&Kg[krow * 128 + kq4 * 8 + i * 32];

  bf16x8 aQ[4];
#pragma unroll
  for (int kt = 0; kt < 4; ++kt)
    aQ[kt] = *(const bf16x8*)&Qg[(l0 + wave * 16 + li) * 128 + kt * 32 + quad * 8];

  f32x4 sc[16] = {};
#pragma unroll
  for (int c = 0; c < 4; ++c) {
    if (c > 0) bar_lgkm();  // prev chunk's LDS readers fully drained
    // write staged K chunk [64 s][128 dh] -> sKV stride 136
#pragma unroll
    for (int i = 0; i < 4; ++i)
      *(uint4*)&sKV[krow * 136 + kq4 * 8 + i * 32] = kreg[c & 1][i];
    // issue next chunk's global loads BEFORE compute; they stay in flight
    // across the raw barriers below (no vmcnt drain)
    if (c < 3) {
#pragma unroll
      for (int i = 0; i < 4; ++i)
        kreg[(c + 1) & 1][i] =
            *(const uint4*)&Kg[((c + 1) * 64 + krow) * 128 + kq4 * 8 + i * 32];
    }
    bar_lgkm();
    __builtin_amdgcn_s_setprio(1);
    // QK^T
#pragma unroll
    for (int kt = 0; kt < 4; ++kt) {
#pragma unroll
      for (int nt = 0; nt < 4; ++nt) {
        bf16x8 bK = *(const bf16x8*)&sKV[(nt * 16 + li) * 136 + kt * 32 + quad * 8];
        sc[c * 4 + nt] = __builtin_amdgcn_mfma_f32_16x16x32_bf16(aQ[kt], bK, sc[c * 4 + nt], 0, 0, 0);
      }
    }
    // term3: G3[r][p] = k[r]·de[p]; banded to sT3[rL][j]
    // (band scatter provably covers every (rL, j) slot read below -> no zeroing needed)
    {
      f32x4 g3[5] = {};
      const int Ab = l0 - (c * 64 + wave * 16) + 240;
#pragma unroll
      for (int kt = 0; kt < 4; ++kt) {
        bf16x8 aK = *(const bf16x8*)&sKV[(wave * 16 + li) * 136 + kt * 32 + quad * 8];
#pragma unroll
        for (int pt = 0; pt < 5; ++pt) {
          int prow = Ab + pt * 16 + li;
          prow = (prow > 510) ? 510 : prow;
          prow = (prow < 0) ? 0 : prow;
          bf16x8 bD = *(const bf16x8*)&de[prow * 128 + kt * 32 + quad * 8];
          g3[pt] = __builtin_amdgcn_mfma_f32_16x16x32_bf16(aK, bD, g3[pt], 0, 0, 0);
        }
      }
#pragma unroll
      for (int pt = 0; pt < 5; ++pt)
#pragma unroll
        for (int r = 0; r < 4; ++r) {
          const int rL = wave * 16 + quad * 4 + r;
          const int j = pt * 16 + li + quad * 4 + r - 15;
          if ((unsigned)j < 64u) sT3[rL * 66 + j] = f2b(g3[pt][r]);
        }
    }
    // term2: G2[l][p] = q[l]·de[p]; banded to sT2[lL][rcol]
    {
      f32x4 g2[5] = {};
      const int A2 = l0 - c * 64 + 192 + wave * 16;
#pragma unroll
      for (int kt = 0; kt < 4; ++kt) {
#pragma unroll
        for (int pt = 0; pt < 5; ++pt) {
          int prow = A2 + pt * 16 + li;
          prow = (prow > 510) ? 510 : prow;
          prow = (prow < 0) ? 0 : prow;
          bf16x8 bD = *(const bf16x8*)&de[prow * 128 + kt * 32 + quad * 8];
          g2[pt] = __builtin_amdgcn_mfma_f32_16x16x32_bf16(aQ[kt], bD, g2[pt], 0, 0, 0);
        }
      }
      __builtin_amdgcn_s_setprio(0);
#pragma unroll
      for (int pt = 0; pt < 5; ++pt)
#pragma unroll
        for (int r = 0; r < 4; ++r) {
          const int lL = wave * 16 + quad * 4 + r;
          const int rcol = quad * 4 + r + 63 - pt * 16 - li;
          if ((unsigned)rcol < 64u) sT2[lL * 66 + rcol] = f2b(g2[pt][r]);
        }
    }
    bar_lgkm();  // band writes visible (LDS only; prefetch stays in flight)
#pragma unroll
    for (int t2 = 0; t2 < 4; ++t2)
#pragma unroll
      for (int r = 0; r < 4; ++r) {
        const int myl = wave * 16 + quad * 4 + r;
        float v3 = sane(b2f(sT3[(t2 * 16 + li) * 66 + myl]), 1e4f);
        float v2 = sane(b2f(sT2[myl * 66 + t2 * 16 + li]), 1e4f);
        sc[c * 4 + t2][r] += v3 + v2;
      }
  }

  // ---- issue V chunk 0 prefetch; overlaps mask load + softmax VALU ----
  const int vrow = tid >> 1, vhalf = tid & 1;
  uint4 vreg[2][4];
#pragma unroll
  for (int i = 0; i < 4; ++i)
    vreg[0][i] = *(const uint4*)&Vg[vrow * 256 + vhalf * 32 + i * 8];

  // mask loaded here (not at kernel top) to keep QK-phase VGPR pressure down
  float mbv[16];
#pragma unroll
  for (int t = 0; t < 16; ++t)
    mbv[t] = (1.0f - b2f(mask[b * 256 + t * 16 + li])) * -1e9f;

  // logits + softmax
#pragma unroll
  for (int t = 0; t < 16; ++t)
#pragma unroll
    for (int r = 0; r < 4; ++r) sc[t][r] = sane(sc[t][r] * scale + mbv[t], 2e9f);
#pragma unroll
  for (int r = 0; r < 4; ++r) {
    float mx = -3.0e38f;
#pragma unroll
    for (int t = 0; t < 16; ++t) mx = fmaxf(mx, sc[t][r]);
#pragma unroll
    for (int m = 1; m < 16; m <<= 1) mx = fmaxf(mx, __shfl_xor(mx, m, 64));
    float s = 0.f;
#pragma unroll
    for (int t = 0; t < 16; ++t) { float e = __expf(sc[t][r] - mx); sc[t][r] = e; s += e; }
#pragma unroll
    for (int m = 1; m < 16; m <<= 1) s += __shfl_xor(s, m, 64);
    const float inv = 1.f / s;
#pragma unroll
    for (int t = 0; t < 16; ++t) sc[t][r] *= inv;
  }

  bar_lgkm();  // band readers done; reuse sP as P [64][264]
#pragma unroll
  for (int t = 0; t < 16; ++t)
#pragma unroll
    for (int r = 0; r < 4; ++r)
      sP[(wave * 16 + quad * 4 + r) * 264 + t * 16 + li] = f2b(sc[t][r]);

  // PV: V chunks [128 dh][64 s] stride 72
  f32x4 ct[8] = {};
#pragma unroll
  for (int c = 0; c < 4; ++c) {
    if (c > 0) bar_lgkm();  // prev chunk's PV reads drained
#pragma unroll
    for (int i = 0; i < 4; ++i)
      *(uint4*)&sKV[vrow * 72 + vhalf * 32 + i * 8] = vreg[c & 1][i];
    if (c < 3) {
#pragma unroll
      for (int i = 0; i < 4; ++i)
        vreg[(c + 1) & 1][i] =
            *(const uint4*)&Vg[vrow * 256 + (c + 1) * 64 + vhalf * 32 + i * 8];
    }
    bar_lgkm();  // covers P writes (c==0) + V chunk writes
    __builtin_amdgcn_s_setprio(1);
#pragma unroll
    for (int ks = 0; ks < 2; ++ks) {
      bf16x8 aF = *(const bf16x8*)&sP[(wave * 16 + li) * 264 + c * 64 + ks * 32 + quad * 8];
#pragma unroll
      for (int nt = 0; nt < 8; ++nt) {
        bf16x8 bV = *(const bf16x8*)&sKV[(nt * 16 + li) * 72 + ks * 32 + quad * 8];
        ct[nt] = __builtin_amdgcn_mfma_f32_16x16x32_bf16(aF, bV, ct[nt], 0, 0, 0);
      }
    }
    __builtin_amdgcn_s_setprio(0);
  }

  bar_lgkm();  // PV reads of sP/sKV done; reuse sP as sC [64][136]
#pragma unroll
  for (int nt = 0; nt < 8; ++nt)
#pragma unroll
    for (int r = 0; r < 4; ++r)
      sP[(wave * 16 + quad * 4 + r) * 136 + nt * 16 + li] = f2b(sane(ct[nt][r], 1e4f));
  bar_lgkm();
  {  // coalesced ctx store: 4 uint4 = 32 elems/thread
    const int row = tid >> 2, seg = tid & 3;
    u16* orow = ctx + ((size_t)(b * 256 + l0 + row)) * 512 + h * 128 + seg * 32;
    const u16* srow = &sP[row * 136 + seg * 32];
#pragma unroll
    for (int i = 0; i < 4; ++i)
      *(uint4*)&orow[i * 8] = *(const uint4*)&srow[i * 8];
  }
}

// ---------------- orchestration ----------------
extern "C" void kernel_launch(void* const* d_in, const int* in_sizes, int n_in,
                              void* d_out, int out_size, void* d_ws, size_t ws_size,
                              hipStream_t stream) {
  (void)in_sizes; (void)n_in; (void)out_size; (void)ws_size;
  const int* ids = (const int*)d_in[0];

  static const int ns[NSEG] = {
      32768, 3072, 512, 512, 512, 512, 65408,
      1048576, 2048, 1048576, 2048, 1048576, 2048, 1048576, 2048,
      2048, 2048, 262144, 512, 262144, 2048, 2048, 2048
  };
  CvtArgs ca;
  int st[NSEG + 1];
  st[0] = 0;
  for (int k = 0; k < NSEG; ++k) { ca.src[k] = d_in[k + 1]; st[k + 1] = st[k] + ns[k]; }
  for (int k = 0; k <= NSEG; ++k) ca.start[k] = st[k];
  const int total = st[NSEG];

  char* W = (char*)d_ws;
  size_t off = 0;
  auto alloc = [&](size_t bytes) { void* p = W + off; off += (bytes + 255) & ~(size_t)255; return p; };
  u16* canon = (u16*)alloc((size_t)total * 2);
  int* flag  = (int*)alloc(256);
  const size_t ND = (size_t)32768 * 512;
  u16* xb   = (u16*)alloc(ND * 2);
  u16* qbf  = (u16*)alloc(ND * 2);
  u16* kbf  = (u16*)alloc(ND * 2);
  u16* vtb  = (u16*)alloc(ND * 2);
  u16* wqT  = (u16*)alloc((size_t)4 * 512 * 512 * 2);
  u16* wkT  = (u16*)alloc((size_t)4 * 512 * 512 * 2);
  u16* wvT  = (u16*)alloc((size_t)4 * 512 * 512 * 2);
  u16* woT  = (u16*)alloc((size_t)4 * 512 * 512 * 2);
  u16* wiT  = (u16*)alloc((size_t)4 * 512 * 128 * 2);
  u16* wo2T = (u16*)alloc((size_t)4 * 128 * 512 * 2);
  u16* ctxb = (u16*)d_out;

  const u16* mask = canon + st[0];
  const u16* inW  = canon + st[1];
  const u16* inB  = canon + st[2];
  const u16* tokE = canon + st[3];
  const u16* eg   = canon + st[4];
  const u16* ebb  = canon + st[5];
  const u16* de   = canon + st[6];
  const u16* Wq   = canon + st[7];
  const u16* bq   = canon + st[8];
  const u16* Wk   = canon + st[9];
  const u16* bk   = canon + st[10];
  const u16* Wv   = canon + st[11];
  const u16* bv   = canon + st[12];
  const u16* Wo   = canon + st[13];
  const u16* bo   = canon + st[14];
  const u16* l1g  = canon + st[15];
  const u16* l1b  = canon + st[16];
  const u16* Wi   = canon + st[17];
  const u16* bi   = canon + st[18];
  const u16* Wo2  = canon + st[19];
  const u16* bo2  = canon + st[20];
  const u16* l2g  = canon + st[21];
  const u16* l2b  = canon + st[22];

  dim3 B256(256);
  detect_dtype<<<1, 1, 0, stream>>>((const unsigned*)d_in[5], flag);
  cvt_all<<<(total + 255) / 256, B256, 0, stream>>>(ca, canon, flag);
  transpose_bf16<<<dim3(16, 16, 4), B256, 0, stream>>>(Wq, wqT, 512, 512);
  transpose_bf16<<<dim3(16, 16, 4), B256, 0, stream>>>(Wk, wkT, 512, 512);
  transpose_bf16<<<dim3(16, 16, 4), B256, 0, stream>>>(Wv, wvT, 512, 512);
  transpose_bf16<<<dim3(16, 16, 4), B256, 0, stream>>>(Wo, woT, 512, 512);
  transpose_bf16<<<dim3(4, 16, 4), B256, 0, stream>>>(Wi, wiT, 512, 128);
  transpose_bf16<<<dim3(16, 4, 4), B256, 0, stream>>>(Wo2, wo2T, 128, 512);
  embed_ln<<<8192, B256, 0, stream>>>(ids, inW, inB, tokE, eg, ebb, xb);

  for (int l = 0; l < 4; ++l) {
    gemm_bt<EPI_QKH><<<dim3(256, 4), B256, 0, stream>>>(xb, wqT + l * 512 * 512, bq + l * 512, qbf, 512, 0);
    gemm_bt<EPI_QKH><<<dim3(256, 4), B256, 0, stream>>>(xb, wkT + l * 512 * 512, bk + l * 512, kbf, 512, 0);
    gemm_bt<EPI_VT><<<dim3(256, 4), B256, 0, stream>>>(xb, wvT + l * 512 * 512, bv + l * 512, vtb, 512, 0);
    attn_kernel<<<dim3(4, 512), B256, 0, stream>>>(qbf, kbf, vtb, de, mask, ctxb);
    gemm_bt<EPI_ROW><<<dim3(256, 4), B256, 0, stream>>>(ctxb, woT + l * 512 * 512, bo + l * 512, qbf, 512, 512);
    add_ln<<<8192, B256, 0, stream>>>(xb, qbf, l1g + l * 512, l1b + l * 512, xb, flag, 0);
    gemm_bt<EPI_GELU><<<dim3(256, 1), B256, 0, stream>>>(xb, wiT + l * 512 * 128, bi + l * 128, kbf, 512, 128);
    gemm_bt<EPI_ROW><<<dim3(256, 4), B256, 0, stream>>>(kbf, wo2T + l * 128 * 512, bo2 + l * 512, vtb, 128, 512);
    add_ln<<<8192, B256, 0, stream>>>(xb, vtb, l2g + l * 512, l2b + l * 512,
                                      (l == 3) ? d_out : (void*)xb, flag, (l == 3) ? 1 : 0);
  }
}

// Round 5
// 1320.398 us; speedup vs baseline: 1.6696x; 1.5644x over previous
//
#include <hip/hip_runtime.h>

typedef unsigned short u16;
typedef __bf16 bf16x8 __attribute__((ext_vector_type(8)));
typedef float f32x4 __attribute__((ext_vector_type(4)));

__device__ __forceinline__ float b2f(u16 u) { return __uint_as_float(((unsigned)u) << 16); }
__device__ __forceinline__ u16 f2b(float f) {
  unsigned i = __float_as_uint(f);
  return (u16)((i + 0x7FFFu + ((i >> 16) & 1u)) >> 16);
}
__device__ __forceinline__ float sane(float x, float lim) {
  float y = fminf(fmaxf(x, -lim), lim);
  return (y != y) ? 0.0f : y;
}
__device__ __forceinline__ float wred(float x) {
#pragma unroll
  for (int m = 1; m < 64; m <<= 1) x += __shfl_xor(x, m, 64);
  return x;
}

// raw barrier that waits LDS ops only (keeps global-load prefetch in flight,
// unlike __syncthreads which drains vmcnt(0))
__device__ __forceinline__ void bar_lgkm() {
  asm volatile("s_waitcnt lgkmcnt(0)" ::: "memory");
  __builtin_amdgcn_s_barrier();
  asm volatile("" ::: "memory");
}

// ---------------- dtype detect ----------------
__global__ void detect_dtype(const unsigned* __restrict__ g_ones, int* __restrict__ flag) {
  *flag = (g_ones[0] == 0x3F800000u) ? 1 : 0;
}

// ---------------- batched convert: all float inputs -> canonical bf16 ----------------
#define NSEG 23
struct CvtArgs {
  const void* src[NSEG];
  int start[NSEG + 1];
};
__global__ __launch_bounds__(256) void cvt_all(CvtArgs a, u16* __restrict__ dst,
                                               const int* __restrict__ flag) {
  const int i = blockIdx.x * 256 + threadIdx.x;
  if (i >= a.start[NSEG]) return;
  int k = 0;
#pragma unroll
  for (int s = 1; s < NSEG; ++s) k += (i >= a.start[s]) ? 1 : 0;
  const int j = i - a.start[k];
  u16 v;
  if (*flag) v = f2b(((const float*)a.src[k])[j]);
  else       v = ((const u16*)a.src[k])[j];
  dst[i] = v;
}

// ---------------- weight transpose ----------------
__global__ __launch_bounds__(256) void transpose_bf16(const u16* __restrict__ src,
                                                      u16* __restrict__ dst, int R, int C) {
  __shared__ u16 tile[32][33];
  const long zo = (long)blockIdx.z * R * C;
  src += zo; dst += zo;
  const int tx = threadIdx.x & 31, ty = threadIdx.x >> 5;
  const int c0 = blockIdx.x * 32, r0 = blockIdx.y * 32;
#pragma unroll
  for (int i = 0; i < 32; i += 8) tile[ty + i][tx] = src[(r0 + ty + i) * C + c0 + tx];
  __syncthreads();
#pragma unroll
  for (int i = 0; i < 32; i += 8) dst[(c0 + ty + i) * R + r0 + tx] = tile[tx][ty + i];
}

// ---------------- embedding + layernorm ----------------
__global__ __launch_bounds__(256) void embed_ln(const int* __restrict__ ids,
    const u16* __restrict__ inW, const u16* __restrict__ inB, const u16* __restrict__ tokE,
    const u16* __restrict__ g, const u16* __restrict__ bb, u16* __restrict__ xb) {
  const int wave = threadIdx.x >> 6, lane = threadIdx.x & 63;
  const int n = blockIdx.x * 4 + wave;
  float idv[6];
#pragma unroll
  for (int f = 0; f < 6; ++f) idv[f] = (float)ids[n * 6 + f];
  float v[8]; float s = 0.f;
#pragma unroll
  for (int j = 0; j < 8; ++j) {
    const int d = j * 64 + lane;
    float a = b2f(inB[d]) + b2f(tokE[d]);
#pragma unroll
    for (int f = 0; f < 6; ++f) a += idv[f] * b2f(inW[f * 512 + d]);
    v[j] = a; s += a;
  }
  s = wred(s);
  const float mu = s * (1.f / 512.f);
  float q = 0.f;
#pragma unroll
  for (int j = 0; j < 8; ++j) { float t = v[j] - mu; q += t * t; }
  q = wred(q);
  const float rstd = rsqrtf(q * (1.f / 512.f) + 1e-12f);
#pragma unroll
  for (int j = 0; j < 8; ++j) {
    const int d = j * 64 + lane;
    xb[n * 512 + d] = f2b(sane((v[j] - mu) * rstd * b2f(g[d]) + b2f(bb[d]), 6e4f));
  }
}

// ---------------- residual add + layernorm ----------------
__global__ __launch_bounds__(256) void add_ln(const u16* __restrict__ xin,
    const u16* __restrict__ add, const u16* __restrict__ g, const u16* __restrict__ bb,
    void* __restrict__ outp, const int* __restrict__ flag, int isfinal) {
  const int wave = threadIdx.x >> 6, lane = threadIdx.x & 63;
  const int n = blockIdx.x * 4 + wave;
  const int base = n * 512 + lane * 8;
  uint4 xa = *(const uint4*)&xin[base];
  uint4 aa = *(const uint4*)&add[base];
  const unsigned* xw = (const unsigned*)&xa;
  const unsigned* aw = (const unsigned*)&aa;
  float v[8]; float s = 0.f;
#pragma unroll
  for (int w = 0; w < 4; ++w) {
    float x0 = b2f((u16)(xw[w] & 0xffff)) + b2f((u16)(aw[w] & 0xffff));
    float x1 = b2f((u16)(xw[w] >> 16)) + b2f((u16)(aw[w] >> 16));
    v[w * 2] = x0; v[w * 2 + 1] = x1; s += x0 + x1;
  }
  s = wred(s);
  const float mu = s * (1.f / 512.f);
  float qs = 0.f;
#pragma unroll
  for (int j = 0; j < 8; ++j) { float t = v[j] - mu; qs += t * t; }
  qs = wred(qs);
  const float rstd = rsqrtf(qs * (1.f / 512.f) + 1e-12f);
  uint4 ga = *(const uint4*)&g[lane * 8];
  uint4 ba = *(const uint4*)&bb[lane * 8];
  const unsigned* gw = (const unsigned*)&ga;
  const unsigned* bw = (const unsigned*)&ba;
  float y[8];
#pragma unroll
  for (int w = 0; w < 4; ++w) {
    y[w * 2]     = sane((v[w * 2] - mu) * rstd * b2f((u16)(gw[w] & 0xffff)) + b2f((u16)(bw[w] & 0xffff)), 6e4f);
    y[w * 2 + 1] = sane((v[w * 2 + 1] - mu) * rstd * b2f((u16)(gw[w] >> 16)) + b2f((u16)(bw[w] >> 16)), 6e4f);
  }
  if (isfinal && *flag) {
    float* of = (float*)outp;
    float4 o0, o1;
    o0.x = y[0]; o0.y = y[1]; o0.z = y[2]; o0.w = y[3];
    o1.x = y[4]; o1.y = y[5]; o1.z = y[6]; o1.w = y[7];
    *(float4*)&of[base] = o0;
    *(float4*)&of[base + 4] = o1;
  } else {
    uint4 o;
    unsigned* ow = (unsigned*)&o;
#pragma unroll
    for (int w = 0; w < 4; ++w)
      ow[w] = (unsigned)f2b(y[w * 2]) | ((unsigned)f2b(y[w * 2 + 1]) << 16);
    *(uint4*)&((u16*)outp)[base] = o;
  }
}

// ---------------- MFMA GEMM: C = A @ BT^T + bias ----------------
// global_load_lds(16B) staging, BK=64, linear LDS dest + pre-swizzled global source
// column (chunk ^= row&7) with matching XOR on ds_read (T2 both-sides rule).
// EPI_B2/EPI_B3: relative-position band GEMMs (A = Q or K rows, BT = dist_emb).
//   B2[bh*256+l][r] = q[l]·de[l-r+255]   (r = l - p + 255)
//   B3[bh*256+r][l] = k[r]·de[l-r+255]   (l = p + r - 255)
// p=511 tail (garbage de row) self-discards via the 0<=idx<256 guard.
enum { EPI_ROW, EPI_GELU, EPI_QKH, EPI_VT, EPI_B2, EPI_B3 };

typedef __attribute__((address_space(1))) const char gld_g;
typedef __attribute__((address_space(3))) char gld_l;

template <int EPI>
__global__ __launch_bounds__(256)
void gemm_bt(const u16* __restrict__ A, const u16* __restrict__ BT,
             const u16* __restrict__ bias, u16* __restrict__ out, int K, int ldo) {
  __shared__ alignas(16) u16 sT[2 * 128 * 64];
  u16* sA = sT;
  u16* sB = sT + 128 * 64;
  const int tid = threadIdx.x;
  const int wave = tid >> 6, lane = tid & 63;
  const int quad = lane >> 4, li = lane & 15;
  const int m0 = blockIdx.x * 128, n0 = blockIdx.y * 128;
  const u16* Ab = A + (size_t)m0 * K;
  const u16* Bb = BT + (size_t)n0 * K;
  const int wm = wave >> 1, wn = wave & 1;
  const int lrow = lane >> 3;           // 0..7 : row within 8-row stage group
  const int lchk = (lane & 7) ^ lrow;   // pre-swizzled 16B chunk index
  f32x4 acc[4][4] = {};
  for (int kt = 0; kt < K; kt += 64) {
    if (kt) __syncthreads();  // prev iteration's ds_reads done before overwrite
#pragma unroll
    for (int i = 0; i < 4; ++i) {
      const int r = wave * 32 + i * 8 + lrow;  // global row this lane fetches
      __builtin_amdgcn_global_load_lds(
          (gld_g*)(Ab + (size_t)r * K + kt + lchk * 8),
          (gld_l*)&sA[(wave * 32 + i * 8) * 64], 16, 0, 0);
      __builtin_amdgcn_global_load_lds(
          (gld_g*)(Bb + (size_t)r * K + kt + lchk * 8),
          (gld_l*)&sB[(wave * 32 + i * 8) * 64], 16, 0, 0);
    }
    asm volatile("s_waitcnt vmcnt(0)" ::: "memory");
    __syncthreads();
#pragma unroll
    for (int h = 0; h < 2; ++h) {
      bf16x8 aF[4], bF[4];
#pragma unroll
      for (int mt = 0; mt < 4; ++mt) {
        const int r = wm * 64 + mt * 16 + li;
        aF[mt] = *(const bf16x8*)&sA[r * 64 + ((h * 32 + quad * 8) ^ ((r & 7) << 3))];
      }
#pragma unroll
      for (int nt = 0; nt < 4; ++nt) {
        const int r = wn * 64 + nt * 16 + li;
        bF[nt] = *(const bf16x8*)&sB[r * 64 + ((h * 32 + quad * 8) ^ ((r & 7) << 3))];
      }
#pragma unroll
      for (int mt = 0; mt < 4; ++mt)
#pragma unroll
        for (int nt = 0; nt < 4; ++nt)
          acc[mt][nt] = __builtin_amdgcn_mfma_f32_16x16x32_bf16(aF[mt], bF[nt], acc[mt][nt], 0, 0, 0);
    }
  }
  if constexpr (EPI == EPI_VT) {
    // transpose through LDS (overlaid on staging buffers) for coalesced [bh][dh][s] stores
    __syncthreads();  // all waves' final ds_reads done before overlay
#pragma unroll
    for (int mt = 0; mt < 4; ++mt)
#pragma unroll
      for (int nt = 0; nt < 4; ++nt)
#pragma unroll
        for (int r = 0; r < 4; ++r) {
          const int ml = wm * 64 + mt * 16 + quad * 4 + r;
          const int nl = wn * 64 + nt * 16 + li;
          float v = sane(acc[mt][nt][r] + b2f(bias[n0 + nl]), 6e4f);
          sT[nl * 128 + (ml ^ ((nl & 7) << 3))] = f2b(v);
        }
    __syncthreads();
    const int bht = (m0 >> 8) * 4 + (n0 >> 7);
    const int s0 = m0 & 255;
    const int dh = tid >> 1, half = tid & 1;
    u16* orow = out + ((size_t)bht * 128 + dh) * 256 + s0 + half * 64;
#pragma unroll
    for (int i = 0; i < 8; ++i) {
      const int idx = dh * 128 + ((half * 64 + i * 8) ^ ((dh & 7) << 3));
      *(uint4*)&orow[i * 8] = *(const uint4*)&sT[idx];
    }
  } else if constexpr (EPI == EPI_B2 || EPI == EPI_B3) {
#pragma unroll
    for (int mt = 0; mt < 4; ++mt) {
#pragma unroll
      for (int nt = 0; nt < 4; ++nt) {
#pragma unroll
        for (int r = 0; r < 4; ++r) {
          const int m = m0 + wm * 64 + mt * 16 + quad * 4 + r;
          const int n = n0 + wn * 64 + nt * 16 + li;
          float v = sane(acc[mt][nt][r], 1e4f);
          const int ll = m & 255;
          if constexpr (EPI == EPI_B2) {
            const int rr2 = ll - n + 255;
            if ((unsigned)rr2 < 256u) out[(size_t)m * 256 + rr2] = f2b(v);
          } else {
            const int lo = n + ll - 255;
            if ((unsigned)lo < 256u) out[(size_t)m * 256 + lo] = f2b(v);
          }
        }
      }
    }
  } else {
#pragma unroll
    for (int mt = 0; mt < 4; ++mt) {
#pragma unroll
      for (int nt = 0; nt < 4; ++nt) {
#pragma unroll
        for (int r = 0; r < 4; ++r) {
          const int m = m0 + wm * 64 + mt * 16 + quad * 4 + r;
          const int n = n0 + wn * 64 + nt * 16 + li;
          float v = sane(acc[mt][nt][r] + b2f(bias[n]), 6e4f);
          if constexpr (EPI == EPI_GELU) v = 0.5f * v * (1.0f + erff(v * 0.70710678118654752f));
          if constexpr (EPI == EPI_ROW || EPI == EPI_GELU) {
            out[m * ldo + n] = f2b(v);
          } else { // EPI_QKH -> [bh][s][dh]
            out[(((m >> 8) * 4 + (n >> 7)) * 256 + (m & 255)) * 128 + (n & 127)] = f2b(v);
          }
        }
      }
    }
  }
}

// ---------------- fused attention ----------------
// term2/term3 now precomputed by EPI_B2/EPI_B3 GEMMs; attn = QK^T + band add + softmax + PV.
// grid = dim3(4, 512): blockIdx.x = lt (same-bh blocks adjacent for K/V L2 reuse).
// LDS 52224 B (3 blocks/CU): sKV 18432 (K [64][136] / V [128][72]);
// sP 33792: B3 chunk tiles 4 x [64][128B] XOR-swz @ c*8192 | later P [64][264] | sC [64][136]
__global__ __launch_bounds__(256, 3)
void attn_kernel(const u16* __restrict__ qb, const u16* __restrict__ kb,
                 const u16* __restrict__ vtb, const u16* __restrict__ b2g,
                 const u16* __restrict__ b3g, const u16* __restrict__ mask,
                 u16* __restrict__ ctx) {
  __shared__ alignas(16) u16 sKV[9216];
  __shared__ alignas(16) u16 sP[16896];
  char* sPb = (char*)sP;
  const int tid = threadIdx.x;
  const int wave = tid >> 6, lane = tid & 63, quad = lane >> 4, li = lane & 15;
  const int lt = blockIdx.x;
  const int bh = blockIdx.y;
  const int b = bh >> 2, h = bh & 3;
  const int l0 = lt * 64;
  const u16* Qg = qb + (size_t)bh * 256 * 128;
  const u16* Kg = kb + (size_t)bh * 256 * 128;
  const u16* Vg = vtb + (size_t)bh * 128 * 256;
  const u16* B2g = b2g + (size_t)bh * 256 * 256;
  const u16* B3g = b3g + (size_t)bh * 256 * 256;
  const float scale = 0.08838834764831845f;

  // ---- prefetch K chunk 0 + B3 tile 0 ----
  const int krow = tid >> 2, kq4 = tid & 3;   // K stage: 4 thr/row
  uint4 kreg[2][4];
#pragma unroll
  for (int i = 0; i < 4; ++i)
    kreg[0][i] = *(const uint4*)&Kg[krow * 128 + kq4 * 8 + i * 32];
  uint4 breg[2][2];  // B3 tile: rows [c*64,c*64+64) x cols [l0,l0+64), 4 thr/row x 32B
#pragma unroll
  for (int h2 = 0; h2 < 2; ++h2)
    breg[0][h2] = *(const uint4*)&B3g[(size_t)krow * 256 + l0 + kq4 * 16 + h2 * 8];

  bf16x8 aQ[4];
#pragma unroll
  for (int kt = 0; kt < 4; ++kt)
    aQ[kt] = *(const bf16x8*)&Qg[(l0 + wave * 16 + li) * 128 + kt * 32 + quad * 8];

  f32x4 sc[16] = {};
#pragma unroll
  for (int c = 0; c < 4; ++c) {
    if (c > 0) bar_lgkm();  // prev chunk's LDS readers fully drained
    // write staged K chunk [64 s][128 dh] -> sKV stride 136
#pragma unroll
    for (int i = 0; i < 4; ++i)
      *(uint4*)&sKV[krow * 136 + kq4 * 8 + i * 32] = kreg[c & 1][i];
    // write staged B3 tile [64][128B] XOR-swz into band arena at c*8192
#pragma unroll
    for (int h2 = 0; h2 < 2; ++h2)
      *(uint4*)&sPb[c * 8192 + ((krow * 128 + kq4 * 32 + h2 * 16) ^ ((krow & 7) << 4))] =
          breg[c & 1][h2];
    // B2 per-thread loads for THIS chunk: issued BEFORE next-chunk prefetch so their
    // vmcnt retires first (in-order) and waiting them doesn't drain the prefetch
    u16 b2v[16];
#pragma unroll
    for (int t2 = 0; t2 < 4; ++t2)
#pragma unroll
      for (int rr = 0; rr < 4; ++rr)
        b2v[t2 * 4 + rr] =
            B2g[(size_t)(l0 + wave * 16 + quad * 4 + rr) * 256 + c * 64 + t2 * 16 + li];
    // issue next chunk's global loads (stay in flight across raw barriers)
    if (c < 3) {
#pragma unroll
      for (int i = 0; i < 4; ++i)
        kreg[(c + 1) & 1][i] =
            *(const uint4*)&Kg[((c + 1) * 64 + krow) * 128 + kq4 * 8 + i * 32];
#pragma unroll
      for (int h2 = 0; h2 < 2; ++h2)
        breg[(c + 1) & 1][h2] =
            *(const uint4*)&B3g[(size_t)((c + 1) * 64 + krow) * 256 + l0 + kq4 * 16 + h2 * 8];
    }
    bar_lgkm();
    __builtin_amdgcn_s_setprio(1);
    // QK^T
#pragma unroll
    for (int kt = 0; kt < 4; ++kt) {
#pragma unroll
      for (int nt = 0; nt < 4; ++nt) {
        bf16x8 bK = *(const bf16x8*)&sKV[(nt * 16 + li) * 136 + kt * 32 + quad * 8];
        sc[c * 4 + nt] = __builtin_amdgcn_mfma_f32_16x16x32_bf16(aQ[kt], bK, sc[c * 4 + nt], 0, 0, 0);
      }
    }
    __builtin_amdgcn_s_setprio(0);
    // band add: B3 from LDS tile (values pre-clamped at GEMM store), B2 from regs
#pragma unroll
    for (int t2 = 0; t2 < 4; ++t2)
#pragma unroll
      for (int rr = 0; rr < 4; ++rr) {
        const int myl = wave * 16 + quad * 4 + rr;
        const int R = t2 * 16 + li;
        float v3 = b2f(*(const u16*)&sPb[c * 8192 + ((R * 128 + myl * 2) ^ ((R & 7) << 4))]);
        float v2 = b2f(b2v[t2 * 4 + rr]);
        sc[c * 4 + t2][rr] += v2 + v3;
      }
  }

  // ---- issue V chunk 0 prefetch; overlaps mask load + softmax VALU ----
  const int vrow = tid >> 1, vhalf = tid & 1;
  uint4 vreg[2][4];
#pragma unroll
  for (int i = 0; i < 4; ++i)
    vreg[0][i] = *(const uint4*)&Vg[vrow * 256 + vhalf * 32 + i * 8];

  float mbv[16];
#pragma unroll
  for (int t = 0; t < 16; ++t)
    mbv[t] = (1.0f - b2f(mask[b * 256 + t * 16 + li])) * -1e9f;

  // logits + softmax
#pragma unroll
  for (int t = 0; t < 16; ++t)
#pragma unroll
    for (int r = 0; r < 4; ++r) sc[t][r] = sane(sc[t][r] * scale + mbv[t], 2e9f);
#pragma unroll
  for (int r = 0; r < 4; ++r) {
    float mx = -3.0e38f;
#pragma unroll
    for (int t = 0; t < 16; ++t) mx = fmaxf(mx, sc[t][r]);
#pragma unroll
    for (int m = 1; m < 16; m <<= 1) mx = fmaxf(mx, __shfl_xor(mx, m, 64));
    float s = 0.f;
#pragma unroll
    for (int t = 0; t < 16; ++t) { float e = __expf(sc[t][r] - mx); sc[t][r] = e; s += e; }
#pragma unroll
    for (int m = 1; m < 16; m <<= 1) s += __shfl_xor(s, m, 64);
    const float inv = 1.f / s;
#pragma unroll
    for (int t = 0; t < 16; ++t) sc[t][r] *= inv;
  }

  bar_lgkm();  // band readers done; reuse sP as P [64][264]
#pragma unroll
  for (int t = 0; t < 16; ++t)
#pragma unroll
    for (int r = 0; r < 4; ++r)
      sP[(wave * 16 + quad * 4 + r) * 264 + t * 16 + li] = f2b(sc[t][r]);

  // PV: V chunks [128 dh][64 s] stride 72
  f32x4 ct[8] = {};
#pragma unroll
  for (int c = 0; c < 4; ++c) {
    if (c > 0) bar_lgkm();  // prev chunk's PV reads drained
#pragma unroll
    for (int i = 0; i < 4; ++i)
      *(uint4*)&sKV[vrow * 72 + vhalf * 32 + i * 8] = vreg[c & 1][i];
    if (c < 3) {
#pragma unroll
      for (int i = 0; i < 4; ++i)
        vreg[(c + 1) & 1][i] =
            *(const uint4*)&Vg[vrow * 256 + (c + 1) * 64 + vhalf * 32 + i * 8];
    }
    bar_lgkm();  // covers P writes (c==0) + V chunk writes
    __builtin_amdgcn_s_setprio(1);
#pragma unroll
    for (int ks = 0; ks < 2; ++ks) {
      bf16x8 aF = *(const bf16x8*)&sP[(wave * 16 + li) * 264 + c * 64 + ks * 32 + quad * 8];
#pragma unroll
      for (int nt = 0; nt < 8; ++nt) {
        bf16x8 bV = *(const bf16x8*)&sKV[(nt * 16 + li) * 72 + ks * 32 + quad * 8];
        ct[nt] = __builtin_amdgcn_mfma_f32_16x16x32_bf16(aF, bV, ct[nt], 0, 0, 0);
      }
    }
    __builtin_amdgcn_s_setprio(0);
  }

  bar_lgkm();  // PV reads of sP/sKV done; reuse sP as sC [64][136]
#pragma unroll
  for (int nt = 0; nt < 8; ++nt)
#pragma unroll
    for (int r = 0; r < 4; ++r)
      sP[(wave * 16 + quad * 4 + r) * 136 + nt * 16 + li] = f2b(sane(ct[nt][r], 1e4f));
  bar_lgkm();
  {  // coalesced ctx store: 4 uint4 = 32 elems/thread
    const int row = tid >> 2, seg = tid & 3;
    u16* orow = ctx + ((size_t)(b * 256 + l0 + row)) * 512 + h * 128 + seg * 32;
    const u16* srow = &sP[row * 136 + seg * 32];
#pragma unroll
    for (int i = 0; i < 4; ++i)
      *(uint4*)&orow[i * 8] = *(const uint4*)&srow[i * 8];
  }
}

// ---------------- orchestration ----------------
extern "C" void kernel_launch(void* const* d_in, const int* in_sizes, int n_in,
                              void* d_out, int out_size, void* d_ws, size_t ws_size,
                              hipStream_t stream) {
  (void)in_sizes; (void)n_in; (void)out_size; (void)ws_size;
  const int* ids = (const int*)d_in[0];

  static const int ns[NSEG] = {
      32768, 3072, 512, 512, 512, 512, 65408,
      1048576, 2048, 1048576, 2048, 1048576, 2048, 1048576, 2048,
      2048, 2048, 262144, 512, 262144, 2048, 2048, 2048
  };
  CvtArgs ca;
  int st[NSEG + 1];
  st[0] = 0;
  for (int k = 0; k < NSEG; ++k) { ca.src[k] = d_in[k + 1]; st[k + 1] = st[k] + ns[k]; }
  for (int k = 0; k <= NSEG; ++k) ca.start[k] = st[k];
  const int total = st[NSEG];

  char* W = (char*)d_ws;
  size_t off = 0;
  auto alloc = [&](size_t bytes) { void* p = W + off; off += (bytes + 255) & ~(size_t)255; return p; };
  u16* canon = (u16*)alloc((size_t)total * 2);
  int* flag  = (int*)alloc(256);
  const size_t ND = (size_t)32768 * 512;
  u16* xb   = (u16*)alloc(ND * 2);
  u16* qbf  = (u16*)alloc(ND * 2);
  u16* kbf  = (u16*)alloc(ND * 2);
  u16* vtb  = (u16*)alloc(ND * 2);
  u16* b2b  = (u16*)alloc((size_t)32768 * 256 * 2);
  u16* b3b  = (u16*)alloc((size_t)32768 * 256 * 2);
  u16* wqT  = (u16*)alloc((size_t)4 * 512 * 512 * 2);
  u16* wkT  = (u16*)alloc((size_t)4 * 512 * 512 * 2);
  u16* wvT  = (u16*)alloc((size_t)4 * 512 * 512 * 2);
  u16* woT  = (u16*)alloc((size_t)4 * 512 * 512 * 2);
  u16* wiT  = (u16*)alloc((size_t)4 * 512 * 128 * 2);
  u16* wo2T = (u16*)alloc((size_t)4 * 128 * 512 * 2);
  u16* ctxb = (u16*)d_out;

  const u16* mask = canon + st[0];
  const u16* inW  = canon + st[1];
  const u16* inB  = canon + st[2];
  const u16* tokE = canon + st[3];
  const u16* eg   = canon + st[4];
  const u16* ebb  = canon + st[5];
  const u16* de   = canon + st[6];
  const u16* Wq   = canon + st[7];
  const u16* bq   = canon + st[8];
  const u16* Wk   = canon + st[9];
  const u16* bk   = canon + st[10];
  const u16* Wv   = canon + st[11];
  const u16* bv   = canon + st[12];
  const u16* Wo   = canon + st[13];
  const u16* bo   = canon + st[14];
  const u16* l1g  = canon + st[15];
  const u16* l1b  = canon + st[16];
  const u16* Wi   = canon + st[17];
  const u16* bi   = canon + st[18];
  const u16* Wo2  = canon + st[19];
  const u16* bo2  = canon + st[20];
  const u16* l2g  = canon + st[21];
  const u16* l2b  = canon + st[22];

  dim3 B256(256);
  detect_dtype<<<1, 1, 0, stream>>>((const unsigned*)d_in[5], flag);
  cvt_all<<<(total + 255) / 256, B256, 0, stream>>>(ca, canon, flag);
  transpose_bf16<<<dim3(16, 16, 4), B256, 0, stream>>>(Wq, wqT, 512, 512);
  transpose_bf16<<<dim3(16, 16, 4), B256, 0, stream>>>(Wk, wkT, 512, 512);
  transpose_bf16<<<dim3(16, 16, 4), B256, 0, stream>>>(Wv, wvT, 512, 512);
  transpose_bf16<<<dim3(16, 16, 4), B256, 0, stream>>>(Wo, woT, 512, 512);
  transpose_bf16<<<dim3(4, 16, 4), B256, 0, stream>>>(Wi, wiT, 512, 128);
  transpose_bf16<<<dim3(16, 4, 4), B256, 0, stream>>>(Wo2, wo2T, 128, 512);
  embed_ln<<<8192, B256, 0, stream>>>(ids, inW, inB, tokE, eg, ebb, xb);

  for (int l = 0; l < 4; ++l) {
    gemm_bt<EPI_QKH><<<dim3(256, 4), B256, 0, stream>>>(xb, wqT + l * 512 * 512, bq + l * 512, qbf, 512, 0);
    gemm_bt<EPI_QKH><<<dim3(256, 4), B256, 0, stream>>>(xb, wkT + l * 512 * 512, bk + l * 512, kbf, 512, 0);
    // relative-position band GEMMs (term2/term3 of the scores)
    gemm_bt<EPI_B2><<<dim3(256, 4), B256, 0, stream>>>(qbf, de, bq, b2b, 128, 0);
    gemm_bt<EPI_B3><<<dim3(256, 4), B256, 0, stream>>>(kbf, de, bk, b3b, 128, 0);
    gemm_bt<EPI_VT><<<dim3(256, 4), B256, 0, stream>>>(xb, wvT + l * 512 * 512, bv + l * 512, vtb, 512, 0);
    attn_kernel<<<dim3(4, 512), B256, 0, stream>>>(qbf, kbf, vtb, b2b, b3b, mask, ctxb);
    gemm_bt<EPI_ROW><<<dim3(256, 4), B256, 0, stream>>>(ctxb, woT + l * 512 * 512, bo + l * 512, qbf, 512, 512);
    add_ln<<<8192, B256, 0, stream>>>(xb, qbf, l1g + l * 512, l1b + l * 512, xb, flag, 0);
    gemm_bt<EPI_GELU><<<dim3(256, 1), B256, 0, stream>>>(xb, wiT + l * 512 * 128, bi + l * 128, kbf, 512, 128);
    gemm_bt<EPI_ROW><<<dim3(256, 4), B256, 0, stream>>>(kbf, wo2T + l * 128 * 512, bo2 + l * 512, vtb, 128, 512);
    add_ln<<<8192, B256, 0, stream>>>(xb, vtb, l2g + l * 512, l2b + l * 512,
                                      (l == 3) ? d_out : (void*)xb, flag, (l == 3) ? 1 : 0);
  }
}